// Round 1
// baseline (1529.037 us; speedup 1.0000x reference)
//
#include <hip/hip_runtime.h>
#include <cstdint>
#include <cstddef>

#define HH 64
#define WW 64
#define CIN 256
#define COUT 256
#define NB 8
#define HW (HH * WW)
#define BN_EPS 1e-5f

// ---------------------------------------------------------------------------
// Kernel 1: NCHW -> NHWC transpose of x.  x[b][c][h][w] -> xs[b][h][w][c]
// grid = NB * 64 * 4 blocks of 256.  64x64 tile via LDS.
// ---------------------------------------------------------------------------
__global__ __launch_bounds__(256) void k_transpose_nhwc(const float* __restrict__ x,
                                                        float* __restrict__ xs) {
  __shared__ float tile[64][65];
  int bid = blockIdx.x;
  int ct = bid & 3;          // c tile (4 x 64)
  int st = (bid >> 2) & 63;  // hw tile (64 x 64)
  int b = bid >> 8;
  int lane = threadIdx.x & 63;
  int grp = threadIdx.x >> 6;  // 0..3
  int c0 = ct * 64, s0 = st * 64;
  const float* xb = x + (size_t)b * CIN * HW;
#pragma unroll
  for (int i = 0; i < 16; ++i) {
    int row = grp * 16 + i;
    tile[row][lane] = xb[(size_t)(c0 + row) * HW + s0 + lane];
  }
  __syncthreads();
  float* xsb = xs + (size_t)b * HW * CIN;
#pragma unroll
  for (int i = 0; i < 16; ++i) {
    int row = grp * 16 + i;  // hw index within tile
    xsb[(size_t)(s0 + row) * CIN + c0 + lane] = tile[lane][row];
  }
}

// ---------------------------------------------------------------------------
// Kernel 2: dc_w [o][c][kh][kw] -> Wt [k][c][o]
// ---------------------------------------------------------------------------
__global__ __launch_bounds__(256) void k_wt(const float* __restrict__ dc_w,
                                            float* __restrict__ Wt) {
  int idx = blockIdx.x * 256 + threadIdx.x;
  if (idx >= COUT * CIN * 9) return;
  int o = idx / (CIN * 9);
  int c = (idx / 9) % CIN;
  int k = idx % 9;
  Wt[((size_t)k * CIN + c) * COUT + o] = dc_w[idx];
}

// ---------------------------------------------------------------------------
// Kernel 3: off_w [ko][c][kh][kw] -> OWt [ko][k][c]
// ---------------------------------------------------------------------------
__global__ __launch_bounds__(256) void k_owt(const float* __restrict__ off_w,
                                             float* __restrict__ OWt) {
  int idx = blockIdx.x * 256 + threadIdx.x;
  if (idx >= 27 * CIN * 9) return;
  int ko = idx / (CIN * 9);
  int c = (idx / 9) % CIN;
  int k = idx % 9;
  OWt[((size_t)ko * 9 + k) * CIN + c] = off_w[idx];
}

// ---------------------------------------------------------------------------
// Kernel 4: offset conv.  om[b][ko][h][w] = sum_{c,kh,kw} xs[b][y][x][c]*OWt[ko][k][c] + off_b
// blockIdx.x = (b*27 + ko)*16 + q ; thread: h = q*4 + tid/64, w = tid%64
// ko uniform per block (provable) -> scalar weight loads.
// ---------------------------------------------------------------------------
__global__ __launch_bounds__(256) void k_offconv(const float* __restrict__ xs,
                                                 const float* __restrict__ OWt,
                                                 const float* __restrict__ off_b,
                                                 float* __restrict__ om) {
  int bid = blockIdx.x;
  int q = bid & 15;
  int ko = (bid >> 4) % 27;
  int b = bid / (27 * 16);
  int w = threadIdx.x & 63;
  int h = q * 4 + (threadIdx.x >> 6);
  const float* xsb = xs + (size_t)b * HW * CIN;
  float4 acc4 = make_float4(0.f, 0.f, 0.f, 0.f);
#pragma unroll
  for (int kh = 0; kh < 3; ++kh) {
    int y = h + kh - 1;
    if (y < 0 || y > HH - 1) continue;  // wave-uniform
#pragma unroll
    for (int kw = 0; kw < 3; ++kw) {
      int xx = w + kw - 1;
      if (xx >= 0 && xx <= WW - 1) {  // per-lane exec mask
        const float4* xrow = (const float4*)(xsb + (size_t)(y * WW + xx) * CIN);
        const float4* wrow = (const float4*)(OWt + ((size_t)ko * 9 + kh * 3 + kw) * CIN);
#pragma unroll 8
        for (int c4 = 0; c4 < CIN / 4; ++c4) {
          float4 xv = xrow[c4];
          float4 wv = wrow[c4];
          acc4.x = fmaf(xv.x, wv.x, acc4.x);
          acc4.y = fmaf(xv.y, wv.y, acc4.y);
          acc4.z = fmaf(xv.z, wv.z, acc4.z);
          acc4.w = fmaf(xv.w, wv.w, acc4.w);
        }
      }
    }
  }
  float acc = acc4.x + acc4.y + acc4.z + acc4.w + off_b[ko];
  om[(((size_t)b * 27 + ko) * HH + h) * WW + w] = acc;
}

// ---------------------------------------------------------------------------
// Kernel 5: fused deformable conv + BN + ReLU.
// One block per (b,h) output row: 64 pixels x 256 out channels.
// ---------------------------------------------------------------------------
__global__ __launch_bounds__(256) void k_main(const float* __restrict__ xs,
                                              const float* __restrict__ om,
                                              const float* __restrict__ Wt,
                                              const float* __restrict__ dc_b,
                                              const float* __restrict__ bn_gamma,
                                              const float* __restrict__ bn_beta,
                                              const float* __restrict__ bn_mean,
                                              const float* __restrict__ bn_var,
                                              float* __restrict__ out) {
  int bid = blockIdx.x;  // b*64 + h
  int h = bid & 63;
  int b = bid >> 6;
  int tid = threadIdx.x;

  __shared__ int pre_off[9][64][4];              // clamped tap element offsets into xs[b]
  __shared__ float pre_w[9][64][4];              // mask-folded bilinear weights (0 if OOB)
  __shared__ __align__(16) float Slds[32][64];   // sampled tile [c][p]
  __shared__ __align__(16) float Wlds[32][256];  // weight tile [c][o]

  // ---- precompute per-(k, w) tap addresses + weights ----
  const float* omb = om + ((size_t)b * 27 * HH + h) * WW;  // channel stride = HW
  for (int item = tid; item < 9 * 64; item += 256) {
    int k = item >> 6;
    int w = item & 63;
    int kh = k / 3, kw = k % 3;
    float offy = omb[(size_t)(2 * k) * HW + w];
    float offx = omb[(size_t)(2 * k + 1) * HW + w];
    float mk = omb[(size_t)(18 + k) * HW + w];
    mk = 1.0f / (1.0f + expf(-mk));
    float py = (float)(h - 1 + kh) + offy;
    float px = (float)(w - 1 + kw) + offx;
    float fy0 = floorf(py), fx0 = floorf(px);
    float wy1 = py - fy0, wx1 = px - fx0;
    int y0 = (int)fy0, x0 = (int)fx0;
    int y1 = y0 + 1, x1 = x0 + 1;
    bool vy0 = (y0 >= 0) && (y0 <= HH - 1);
    bool vy1 = (y1 >= 0) && (y1 <= HH - 1);
    bool vx0 = (x0 >= 0) && (x0 <= WW - 1);
    bool vx1 = (x1 >= 0) && (x1 <= WW - 1);
    int y0c = min(max(y0, 0), HH - 1), y1c = min(max(y1, 0), HH - 1);
    int x0c = min(max(x0, 0), WW - 1), x1c = min(max(x1, 0), WW - 1);
    pre_w[k][w][0] = (1.f - wy1) * (1.f - wx1) * mk * ((vy0 && vx0) ? 1.f : 0.f);
    pre_w[k][w][1] = (1.f - wy1) * wx1 * mk * ((vy0 && vx1) ? 1.f : 0.f);
    pre_w[k][w][2] = wy1 * (1.f - wx1) * mk * ((vy1 && vx0) ? 1.f : 0.f);
    pre_w[k][w][3] = wy1 * wx1 * mk * ((vy1 && vx1) ? 1.f : 0.f);
    pre_off[k][w][0] = (y0c * WW + x0c) * CIN;
    pre_off[k][w][1] = (y0c * WW + x1c) * CIN;
    pre_off[k][w][2] = (y1c * WW + x0c) * CIN;
    pre_off[k][w][3] = (y1c * WW + x1c) * CIN;
  }

  float acc[8][8];
#pragma unroll
  for (int i = 0; i < 8; ++i)
#pragma unroll
    for (int j = 0; j < 8; ++j) acc[i][j] = 0.f;

  const float* xsb = xs + (size_t)b * HW * CIN;
  int p_base = (tid >> 5) * 8;  // 0..56
  int o_base = (tid & 31) * 8;  // 0..248
  int sp = tid & 63;            // staging pixel
  int sc0 = (tid >> 6) * 8;     // staging channel base (within 32-tile)

  for (int k = 0; k < 9; ++k) {
    for (int ct = 0; ct < 8; ++ct) {
      __syncthreads();  // protect LDS reuse (also covers precompute on first iter)
      // ---- stage S[32][64]: bilinear gather ----
      {
        float s[8] = {0.f, 0.f, 0.f, 0.f, 0.f, 0.f, 0.f, 0.f};
        const int* po = pre_off[k][sp];
        const float* pw = pre_w[k][sp];
#pragma unroll
        for (int t = 0; t < 4; ++t) {
          const float* src = xsb + po[t] + ct * 32 + sc0;
          float4 a = *(const float4*)(src);
          float4 bb = *(const float4*)(src + 4);
          float wt = pw[t];
          s[0] = fmaf(wt, a.x, s[0]);
          s[1] = fmaf(wt, a.y, s[1]);
          s[2] = fmaf(wt, a.z, s[2]);
          s[3] = fmaf(wt, a.w, s[3]);
          s[4] = fmaf(wt, bb.x, s[4]);
          s[5] = fmaf(wt, bb.y, s[5]);
          s[6] = fmaf(wt, bb.z, s[6]);
          s[7] = fmaf(wt, bb.w, s[7]);
        }
#pragma unroll
        for (int j = 0; j < 8; ++j) Slds[sc0 + j][sp] = s[j];
      }
      // ---- stage W[32][256] ----
      {
        const float4* src = (const float4*)(Wt + ((size_t)k * CIN + ct * 32) * COUT);
        float4* dst = (float4*)Wlds;
#pragma unroll
        for (int i = 0; i < 8; ++i) dst[tid + i * 256] = src[tid + i * 256];
      }
      __syncthreads();
      // ---- compute: acc[i][j] += S[c][p_base+i] * W[c][o_base+j] ----
#pragma unroll 4
      for (int c = 0; c < 32; ++c) {
        float4 s0 = *(const float4*)&Slds[c][p_base];
        float4 s1 = *(const float4*)&Slds[c][p_base + 4];
        float4 w0 = *(const float4*)&Wlds[c][o_base];
        float4 w1 = *(const float4*)&Wlds[c][o_base + 4];
        float sv[8] = {s0.x, s0.y, s0.z, s0.w, s1.x, s1.y, s1.z, s1.w};
        float wv[8] = {w0.x, w0.y, w0.z, w0.w, w1.x, w1.y, w1.z, w1.w};
#pragma unroll
        for (int i = 0; i < 8; ++i)
#pragma unroll
          for (int j = 0; j < 8; ++j) acc[i][j] = fmaf(sv[i], wv[j], acc[i][j]);
      }
    }
  }

  // ---- epilogue: BN fold + ReLU, vectorized stores ----
#pragma unroll
  for (int j = 0; j < 8; ++j) {
    int o = o_base + j;
    float sc = bn_gamma[o] * rsqrtf(bn_var[o] + BN_EPS);
    float bi = bn_beta[o] - bn_mean[o] * sc + dc_b[o] * sc;
    float4 v0, v1;
    v0.x = fmaxf(fmaf(acc[0][j], sc, bi), 0.f);
    v0.y = fmaxf(fmaf(acc[1][j], sc, bi), 0.f);
    v0.z = fmaxf(fmaf(acc[2][j], sc, bi), 0.f);
    v0.w = fmaxf(fmaf(acc[3][j], sc, bi), 0.f);
    v1.x = fmaxf(fmaf(acc[4][j], sc, bi), 0.f);
    v1.y = fmaxf(fmaf(acc[5][j], sc, bi), 0.f);
    v1.z = fmaxf(fmaf(acc[6][j], sc, bi), 0.f);
    v1.w = fmaxf(fmaf(acc[7][j], sc, bi), 0.f);
    float* op = out + (((size_t)b * COUT + o) * HH + h) * WW + p_base;
    *(float4*)op = v0;
    *(float4*)(op + 4) = v1;
  }
}

// ---------------------------------------------------------------------------
extern "C" void kernel_launch(void* const* d_in, const int* in_sizes, int n_in,
                              void* d_out, int out_size, void* d_ws, size_t ws_size,
                              hipStream_t stream) {
  const float* x = (const float*)d_in[0];
  const float* off_w = (const float*)d_in[1];
  const float* off_b = (const float*)d_in[2];
  const float* dc_w = (const float*)d_in[3];
  const float* dc_b = (const float*)d_in[4];
  const float* bn_gamma = (const float*)d_in[5];
  const float* bn_beta = (const float*)d_in[6];
  const float* bn_mean = (const float*)d_in[7];
  const float* bn_var = (const float*)d_in[8];
  float* out = (float*)d_out;

  // workspace layout (floats)
  float* ws = (float*)d_ws;
  float* xs = ws;                                   // 8*4096*256       = 8388608
  float* om = xs + (size_t)NB * HW * CIN;           // 8*27*4096        = 884736
  float* Wt = om + (size_t)NB * 27 * HW;            // 9*256*256        = 589824
  float* OWt = Wt + (size_t)9 * CIN * COUT;         // 27*9*256         = 62208

  k_transpose_nhwc<<<NB * 64 * 4, 256, 0, stream>>>(x, xs);
  k_wt<<<(COUT * CIN * 9 + 255) / 256, 256, 0, stream>>>(dc_w, Wt);
  k_owt<<<(27 * CIN * 9 + 255) / 256, 256, 0, stream>>>(off_w, OWt);
  k_offconv<<<NB * 27 * 16, 256, 0, stream>>>(xs, OWt, off_b, om);
  k_main<<<NB * HH, 256, 0, stream>>>(xs, om, Wt, dc_b, bn_gamma, bn_beta, bn_mean,
                                      bn_var, out);
}

// Round 2
// 781.119 us; speedup vs baseline: 1.9575x; 1.9575x over previous
//
#include <hip/hip_runtime.h>
#include <cstdint>
#include <cstddef>

#define HH 64
#define WW 64
#define CIN 256
#define COUT 256
#define NB 8
#define HW (HH * WW)
#define BN_EPS 1e-5f

// ---------------------------------------------------------------------------
// Kernel 1: NCHW -> NHWC transpose of x.  x[b][c][h][w] -> xs[b][h][w][c]
// grid = NB * 64 * 4 blocks of 256.  64x64 tile via LDS.
// ---------------------------------------------------------------------------
__global__ __launch_bounds__(256) void k_transpose_nhwc(const float* __restrict__ x,
                                                        float* __restrict__ xs) {
  __shared__ float tile[64][65];
  int bid = blockIdx.x;
  int ct = bid & 3;          // c tile (4 x 64)
  int st = (bid >> 2) & 63;  // hw tile (64 x 64)
  int b = bid >> 8;
  int lane = threadIdx.x & 63;
  int grp = threadIdx.x >> 6;  // 0..3
  int c0 = ct * 64, s0 = st * 64;
  const float* xb = x + (size_t)b * CIN * HW;
#pragma unroll
  for (int i = 0; i < 16; ++i) {
    int row = grp * 16 + i;
    tile[row][lane] = xb[(size_t)(c0 + row) * HW + s0 + lane];
  }
  __syncthreads();
  float* xsb = xs + (size_t)b * HW * CIN;
#pragma unroll
  for (int i = 0; i < 16; ++i) {
    int row = grp * 16 + i;  // hw index within tile
    xsb[(size_t)(s0 + row) * CIN + c0 + lane] = tile[lane][row];
  }
}

// ---------------------------------------------------------------------------
// Kernel 2: dc_w [o][c][kh][kw] -> Wt [k][c][o]
// ---------------------------------------------------------------------------
__global__ __launch_bounds__(256) void k_wt(const float* __restrict__ dc_w,
                                            float* __restrict__ Wt) {
  int idx = blockIdx.x * 256 + threadIdx.x;
  if (idx >= COUT * CIN * 9) return;
  int o = idx / (CIN * 9);
  int c = (idx / 9) % CIN;
  int k = idx % 9;
  Wt[((size_t)k * CIN + c) * COUT + o] = dc_w[idx];
}

// ---------------------------------------------------------------------------
// Kernel 3: off_w [ko][c][kh][kw] -> OW2 [c][ko][t]  (t = kh*3+kw)
// Per-c contiguous 243-float block -> wave-uniform scalar loads in k_offconv.
// ---------------------------------------------------------------------------
__global__ __launch_bounds__(256) void k_owt(const float* __restrict__ off_w,
                                             float* __restrict__ OW2) {
  int idx = blockIdx.x * 256 + threadIdx.x;
  if (idx >= 27 * CIN * 9) return;
  int ko = idx / (CIN * 9);
  int c = (idx / 9) % CIN;
  int t = idx % 9;
  OW2[((size_t)c * 27 + ko) * 9 + t] = off_w[idx];
}

// ---------------------------------------------------------------------------
// Kernel 4: offset conv, direct NCHW.  One block per (b,h): 64 px x 27 ko.
// lane = w -> coalesced row loads; w+-1 taps via shuffles; 27 reg accumulators;
// 4 waves split c 4x64; LDS cross-wave reduce.
// ---------------------------------------------------------------------------
__global__ __launch_bounds__(256) void k_offconv(const float* __restrict__ x,
                                                 const float* __restrict__ OW2,
                                                 const float* __restrict__ off_b,
                                                 float* __restrict__ om) {
  int bid = blockIdx.x;  // b*64 + h
  int h = bid & 63;
  int b = bid >> 6;
  int w = threadIdx.x & 63;
  int wave = threadIdx.x >> 6;  // c-chunk 0..3

  float acc[27];
#pragma unroll
  for (int i = 0; i < 27; ++i) acc[i] = 0.f;

  const float* xb = x + (size_t)b * CIN * HW;
  bool up = (h > 0), dn = (h < HH - 1);

  for (int ci = 0; ci < 64; ++ci) {
    int c = wave * 64 + ci;
    const float* xc = xb + (size_t)c * HW;
    float r0 = up ? xc[(h - 1) * WW + w] : 0.f;
    float r1 = xc[h * WW + w];
    float r2 = dn ? xc[(h + 1) * WW + w] : 0.f;
    float v[9];
    v[1] = r0; v[4] = r1; v[7] = r2;
    v[0] = __shfl_up(r0, 1);
    v[3] = __shfl_up(r1, 1);
    v[6] = __shfl_up(r2, 1);
    v[2] = __shfl_down(r0, 1);
    v[5] = __shfl_down(r1, 1);
    v[8] = __shfl_down(r2, 1);
    if (w == 0) { v[0] = 0.f; v[3] = 0.f; v[6] = 0.f; }
    if (w == WW - 1) { v[2] = 0.f; v[5] = 0.f; v[8] = 0.f; }
    const float* wc = OW2 + (size_t)c * 243;  // wave-uniform address
#pragma unroll
    for (int ko = 0; ko < 27; ++ko) {
      const float* wk = wc + ko * 9;
#pragma unroll
      for (int t = 0; t < 9; ++t) acc[ko] = fmaf(v[t], wk[t], acc[ko]);
    }
  }

  __shared__ float red[4][27][64];
#pragma unroll
  for (int ko = 0; ko < 27; ++ko) red[wave][ko][w] = acc[ko];
  __syncthreads();
  for (int idx = threadIdx.x; idx < 27 * 64; idx += 256) {
    int ko = idx >> 6;
    int ww = idx & 63;
    float s = red[0][ko][ww] + red[1][ko][ww] + red[2][ko][ww] + red[3][ko][ww] +
              off_b[ko];
    om[(((size_t)b * 27 + ko) * HH + h) * WW + ww] = s;
  }
}

// ---------------------------------------------------------------------------
// Kernel 5: fused deformable conv + BN + ReLU.
// One block per (b,h) output row: 64 pixels x 256 out channels.
// ---------------------------------------------------------------------------
__global__ __launch_bounds__(256) void k_main(const float* __restrict__ xs,
                                              const float* __restrict__ om,
                                              const float* __restrict__ Wt,
                                              const float* __restrict__ dc_b,
                                              const float* __restrict__ bn_gamma,
                                              const float* __restrict__ bn_beta,
                                              const float* __restrict__ bn_mean,
                                              const float* __restrict__ bn_var,
                                              float* __restrict__ out) {
  int bid = blockIdx.x;  // b*64 + h
  int h = bid & 63;
  int b = bid >> 6;
  int tid = threadIdx.x;

  __shared__ int pre_off[9][64][4];              // clamped tap element offsets into xs[b]
  __shared__ float pre_w[9][64][4];              // mask-folded bilinear weights (0 if OOB)
  __shared__ __align__(16) float Slds[32][64];   // sampled tile [c][p]
  __shared__ __align__(16) float Wlds[32][256];  // weight tile [c][o]

  // ---- precompute per-(k, w) tap addresses + weights ----
  const float* omb = om + ((size_t)b * 27 * HH + h) * WW;  // channel stride = HW
  for (int item = tid; item < 9 * 64; item += 256) {
    int k = item >> 6;
    int w = item & 63;
    int kh = k / 3, kw = k % 3;
    float offy = omb[(size_t)(2 * k) * HW + w];
    float offx = omb[(size_t)(2 * k + 1) * HW + w];
    float mk = omb[(size_t)(18 + k) * HW + w];
    mk = 1.0f / (1.0f + expf(-mk));
    float py = (float)(h - 1 + kh) + offy;
    float px = (float)(w - 1 + kw) + offx;
    float fy0 = floorf(py), fx0 = floorf(px);
    float wy1 = py - fy0, wx1 = px - fx0;
    int y0 = (int)fy0, x0 = (int)fx0;
    int y1 = y0 + 1, x1 = x0 + 1;
    bool vy0 = (y0 >= 0) && (y0 <= HH - 1);
    bool vy1 = (y1 >= 0) && (y1 <= HH - 1);
    bool vx0 = (x0 >= 0) && (x0 <= WW - 1);
    bool vx1 = (x1 >= 0) && (x1 <= WW - 1);
    int y0c = min(max(y0, 0), HH - 1), y1c = min(max(y1, 0), HH - 1);
    int x0c = min(max(x0, 0), WW - 1), x1c = min(max(x1, 0), WW - 1);
    pre_w[k][w][0] = (1.f - wy1) * (1.f - wx1) * mk * ((vy0 && vx0) ? 1.f : 0.f);
    pre_w[k][w][1] = (1.f - wy1) * wx1 * mk * ((vy0 && vx1) ? 1.f : 0.f);
    pre_w[k][w][2] = wy1 * (1.f - wx1) * mk * ((vy1 && vx0) ? 1.f : 0.f);
    pre_w[k][w][3] = wy1 * wx1 * mk * ((vy1 && vx1) ? 1.f : 0.f);
    pre_off[k][w][0] = (y0c * WW + x0c) * CIN;
    pre_off[k][w][1] = (y0c * WW + x1c) * CIN;
    pre_off[k][w][2] = (y1c * WW + x0c) * CIN;
    pre_off[k][w][3] = (y1c * WW + x1c) * CIN;
  }

  float acc[8][8];
#pragma unroll
  for (int i = 0; i < 8; ++i)
#pragma unroll
    for (int j = 0; j < 8; ++j) acc[i][j] = 0.f;

  const float* xsb = xs + (size_t)b * HW * CIN;
  int p_base = (tid >> 5) * 8;  // 0..56
  int o_base = (tid & 31) * 8;  // 0..248
  int sp = tid & 63;            // staging pixel
  int sc0 = (tid >> 6) * 8;     // staging channel base (within 32-tile)

  for (int k = 0; k < 9; ++k) {
    for (int ct = 0; ct < 8; ++ct) {
      __syncthreads();  // protect LDS reuse (also covers precompute on first iter)
      // ---- stage S[32][64]: bilinear gather ----
      {
        float s[8] = {0.f, 0.f, 0.f, 0.f, 0.f, 0.f, 0.f, 0.f};
        const int* po = pre_off[k][sp];
        const float* pw = pre_w[k][sp];
#pragma unroll
        for (int t = 0; t < 4; ++t) {
          const float* src = xsb + po[t] + ct * 32 + sc0;
          float4 a = *(const float4*)(src);
          float4 bb = *(const float4*)(src + 4);
          float wt = pw[t];
          s[0] = fmaf(wt, a.x, s[0]);
          s[1] = fmaf(wt, a.y, s[1]);
          s[2] = fmaf(wt, a.z, s[2]);
          s[3] = fmaf(wt, a.w, s[3]);
          s[4] = fmaf(wt, bb.x, s[4]);
          s[5] = fmaf(wt, bb.y, s[5]);
          s[6] = fmaf(wt, bb.z, s[6]);
          s[7] = fmaf(wt, bb.w, s[7]);
        }
#pragma unroll
        for (int j = 0; j < 8; ++j) Slds[sc0 + j][sp] = s[j];
      }
      // ---- stage W[32][256] ----
      {
        const float4* src = (const float4*)(Wt + ((size_t)k * CIN + ct * 32) * COUT);
        float4* dst = (float4*)Wlds;
#pragma unroll
        for (int i = 0; i < 8; ++i) dst[tid + i * 256] = src[tid + i * 256];
      }
      __syncthreads();
      // ---- compute: acc[i][j] += S[c][p_base+i] * W[c][o_base+j] ----
#pragma unroll 4
      for (int c = 0; c < 32; ++c) {
        float4 s0 = *(const float4*)&Slds[c][p_base];
        float4 s1 = *(const float4*)&Slds[c][p_base + 4];
        float4 w0 = *(const float4*)&Wlds[c][o_base];
        float4 w1 = *(const float4*)&Wlds[c][o_base + 4];
        float sv[8] = {s0.x, s0.y, s0.z, s0.w, s1.x, s1.y, s1.z, s1.w};
        float wv[8] = {w0.x, w0.y, w0.z, w0.w, w1.x, w1.y, w1.z, w1.w};
#pragma unroll
        for (int i = 0; i < 8; ++i)
#pragma unroll
          for (int j = 0; j < 8; ++j) acc[i][j] = fmaf(sv[i], wv[j], acc[i][j]);
      }
    }
  }

  // ---- epilogue: BN fold + ReLU, vectorized stores ----
#pragma unroll
  for (int j = 0; j < 8; ++j) {
    int o = o_base + j;
    float sc = bn_gamma[o] * rsqrtf(bn_var[o] + BN_EPS);
    float bi = bn_beta[o] - bn_mean[o] * sc + dc_b[o] * sc;
    float4 v0, v1;
    v0.x = fmaxf(fmaf(acc[0][j], sc, bi), 0.f);
    v0.y = fmaxf(fmaf(acc[1][j], sc, bi), 0.f);
    v0.z = fmaxf(fmaf(acc[2][j], sc, bi), 0.f);
    v0.w = fmaxf(fmaf(acc[3][j], sc, bi), 0.f);
    v1.x = fmaxf(fmaf(acc[4][j], sc, bi), 0.f);
    v1.y = fmaxf(fmaf(acc[5][j], sc, bi), 0.f);
    v1.z = fmaxf(fmaf(acc[6][j], sc, bi), 0.f);
    v1.w = fmaxf(fmaf(acc[7][j], sc, bi), 0.f);
    float* op = out + (((size_t)b * COUT + o) * HH + h) * WW + p_base;
    *(float4*)op = v0;
    *(float4*)(op + 4) = v1;
  }
}

// ---------------------------------------------------------------------------
extern "C" void kernel_launch(void* const* d_in, const int* in_sizes, int n_in,
                              void* d_out, int out_size, void* d_ws, size_t ws_size,
                              hipStream_t stream) {
  const float* x = (const float*)d_in[0];
  const float* off_w = (const float*)d_in[1];
  const float* off_b = (const float*)d_in[2];
  const float* dc_w = (const float*)d_in[3];
  const float* dc_b = (const float*)d_in[4];
  const float* bn_gamma = (const float*)d_in[5];
  const float* bn_beta = (const float*)d_in[6];
  const float* bn_mean = (const float*)d_in[7];
  const float* bn_var = (const float*)d_in[8];
  float* out = (float*)d_out;

  // workspace layout (floats)
  float* ws = (float*)d_ws;
  float* xs = ws;                            // 8*4096*256 = 8388608
  float* om = xs + (size_t)NB * HW * CIN;    // 8*27*4096  = 884736
  float* Wt = om + (size_t)NB * 27 * HW;     // 9*256*256  = 589824
  float* OW2 = Wt + (size_t)9 * CIN * COUT;  // 256*27*9   = 62208

  k_transpose_nhwc<<<NB * 64 * 4, 256, 0, stream>>>(x, xs);
  k_wt<<<(COUT * CIN * 9 + 255) / 256, 256, 0, stream>>>(dc_w, Wt);
  k_owt<<<(27 * CIN * 9 + 255) / 256, 256, 0, stream>>>(off_w, OW2);
  k_offconv<<<NB * HH, 256, 0, stream>>>(x, OW2, off_b, om);
  k_main<<<NB * HH, 256, 0, stream>>>(xs, om, Wt, dc_b, bn_gamma, bn_beta, bn_mean,
                                      bn_var, out);
}

// Round 3
// 507.820 us; speedup vs baseline: 3.0110x; 1.5382x over previous
//
#include <hip/hip_runtime.h>
#include <hip/hip_bf16.h>
#include <cstdint>
#include <cstddef>

#define HH 64
#define WW 64
#define CIN 256
#define COUT 256
#define NB 8
#define HW (HH * WW)
#define BN_EPS 1e-5f

typedef __attribute__((ext_vector_type(8))) short s16x8;
typedef __attribute__((ext_vector_type(8))) unsigned short u16x8;
typedef __attribute__((ext_vector_type(4))) float f32x4;

static __device__ __forceinline__ float bf2f(unsigned short u) {
  unsigned int v = ((unsigned int)u) << 16;
  return __builtin_bit_cast(float, v);
}
static __device__ __forceinline__ unsigned short f2bf(float f) {
  __hip_bfloat16 h = __float2bfloat16(f);
  return __builtin_bit_cast(unsigned short, h);
}

// ---------------------------------------------------------------------------
// Kernel 1: x NCHW fp32 -> xbf NHWC bf16.
// ---------------------------------------------------------------------------
__global__ __launch_bounds__(256) void k_tr(const float* __restrict__ x,
                                            unsigned short* __restrict__ xbf) {
  __shared__ float tile[64][65];
  int bid = blockIdx.x;
  int ct = bid & 3;
  int st = (bid >> 2) & 63;
  int b = bid >> 8;
  int lane = threadIdx.x & 63;
  int grp = threadIdx.x >> 6;
  int c0 = ct * 64, s0 = st * 64;
  const float* xb = x + (size_t)b * CIN * HW;
#pragma unroll
  for (int i = 0; i < 16; ++i) {
    int row = grp * 16 + i;
    tile[row][lane] = xb[(size_t)(c0 + row) * HW + s0 + lane];
  }
  __syncthreads();
  unsigned short* xo = xbf + (size_t)b * HW * CIN;
#pragma unroll
  for (int i = 0; i < 16; ++i) {
    int row = grp * 16 + i;
    xo[(size_t)(s0 + row) * CIN + c0 + lane] = f2bf(tile[lane][row]);
  }
}

// ---------------------------------------------------------------------------
// Kernel 2: dc_w [o][c][3][3] fp32 -> Wbf [k][o][c] bf16 (c contiguous)
// ---------------------------------------------------------------------------
__global__ __launch_bounds__(256) void k_wt(const float* __restrict__ dc_w,
                                            unsigned short* __restrict__ Wbf) {
  int idx = blockIdx.x * 256 + threadIdx.x;  // (k*256+o)*256+c
  if (idx >= 9 * COUT * CIN) return;
  int k = idx >> 16;
  int o = (idx >> 8) & 255;
  int c = idx & 255;
  Wbf[idx] = f2bf(dc_w[((size_t)o * CIN + c) * 9 + k]);
}

// ---------------------------------------------------------------------------
// Kernel 3: off_w [ko][c][3][3] -> OW2 [c][256] fp32 (j = ko*9+t, pad 243..255)
// ---------------------------------------------------------------------------
__global__ __launch_bounds__(256) void k_owt(const float* __restrict__ off_w,
                                             float* __restrict__ OW2) {
  int idx = blockIdx.x * 256 + threadIdx.x;
  if (idx >= CIN * 256) return;
  int c = idx >> 8, j = idx & 255;
  float v = 0.f;
  if (j < 243) {
    int ko = j / 9, t = j % 9;
    v = off_w[((size_t)ko * CIN + c) * 9 + t];
  }
  OW2[idx] = v;
}

// ---------------------------------------------------------------------------
// Kernel 4: fold BN + conv bias: sc = gamma*rsqrt(var+eps); bi = beta+(dc_b-mean)*sc
// ---------------------------------------------------------------------------
__global__ void k_bn(const float* __restrict__ g, const float* __restrict__ be,
                     const float* __restrict__ m, const float* __restrict__ va,
                     const float* __restrict__ db, float* __restrict__ sc,
                     float* __restrict__ bi) {
  int o = threadIdx.x;
  float s = g[o] * rsqrtf(va[o] + BN_EPS);
  sc[o] = s;
  bi[o] = be[o] + (db[o] - m[o]) * s;
}

// ---------------------------------------------------------------------------
// Kernel 5: offset conv, direct NCHW; scalar (s_load) weights via readfirstlane.
// ---------------------------------------------------------------------------
__global__ __launch_bounds__(256) void k_offconv(const float* __restrict__ x,
                                                 const float* __restrict__ OW2,
                                                 const float* __restrict__ off_b,
                                                 float* __restrict__ om) {
  int bid = blockIdx.x;  // b*64 + h
  int h = bid & 63;
  int b = bid >> 6;
  int w = threadIdx.x & 63;
  int wave = threadIdx.x >> 6;

  float acc[27];
#pragma unroll
  for (int i = 0; i < 27; ++i) acc[i] = 0.f;

  const float* xb = x + (size_t)b * CIN * HW;
  bool up = (h > 0), dn = (h < HH - 1);
  int cb = wave * 64;

  for (int ci = 0; ci < 64; ++ci) {
    int c = cb + ci;
    const float* xc = xb + (size_t)c * HW;
    float r0 = up ? xc[(h - 1) * WW + w] : 0.f;
    float r1 = xc[h * WW + w];
    float r2 = dn ? xc[(h + 1) * WW + w] : 0.f;
    float v[9];
    v[1] = r0; v[4] = r1; v[7] = r2;
    v[0] = __shfl_up(r0, 1);
    v[3] = __shfl_up(r1, 1);
    v[6] = __shfl_up(r2, 1);
    v[2] = __shfl_down(r0, 1);
    v[5] = __shfl_down(r1, 1);
    v[8] = __shfl_down(r2, 1);
    if (w == 0) { v[0] = 0.f; v[3] = 0.f; v[6] = 0.f; }
    if (w == WW - 1) { v[2] = 0.f; v[5] = 0.f; v[8] = 0.f; }
    // wave-uniform scalar weight base -> s_load + SGPR-operand FMAs
    const float* wk = OW2 + ((size_t)__builtin_amdgcn_readfirstlane(c) << 8);
#pragma unroll
    for (int ko = 0; ko < 27; ++ko) {
#pragma unroll
      for (int t = 0; t < 9; ++t) acc[ko] = fmaf(v[t], wk[ko * 9 + t], acc[ko]);
    }
  }

  __shared__ float red[4][27][64];
#pragma unroll
  for (int ko = 0; ko < 27; ++ko) red[wave][ko][w] = acc[ko];
  __syncthreads();
  for (int idx = threadIdx.x; idx < 27 * 64; idx += 256) {
    int ko = idx >> 6;
    int ww = idx & 63;
    om[(((size_t)b * 27 + ko) * HH + h) * WW + ww] =
        red[0][ko][ww] + red[1][ko][ww] + red[2][ko][ww] + red[3][ko][ww] + off_b[ko];
  }
}

// ---------------------------------------------------------------------------
// Kernel 6: fused deformable conv (bf16 MFMA) + BN + ReLU.
// Block = (b,h): 64 px x 256 o.  4 waves, each 64 o x 64 p, acc 4x4 f32x4.
// S[64p][256c] bf16 in LDS, XOR-swizzled (chunk ^ (p&7)) -> conflict-free b128.
// A-fragments read directly from global Wbf[k][o][c] (L2-resident, used once).
// ---------------------------------------------------------------------------
__global__ __launch_bounds__(256, 2) void k_main(
    const unsigned short* __restrict__ xbf, const float* __restrict__ om,
    const unsigned short* __restrict__ Wbf, const float* __restrict__ bnsc,
    const float* __restrict__ bnbi, float* __restrict__ out) {
  int bid = blockIdx.x;  // b*64 + h
  int h = bid & 63;
  int b = bid >> 6;
  int tid = threadIdx.x;
  int lane = tid & 63;
  int wave = tid >> 6;

  __shared__ int pre_off[9][64][4];
  __shared__ float pre_w[9][64][4];
  __shared__ __align__(16) unsigned short S[64][256];

  // ---- precompute per-(k,w) tap offsets (ushort elems) + mask-folded weights
  const float* omb = om + ((size_t)b * 27 * HH + h) * WW;
  for (int item = tid; item < 9 * 64; item += 256) {
    int k = item >> 6;
    int w = item & 63;
    int kh = k / 3, kw = k % 3;
    float offy = omb[(size_t)(2 * k) * HW + w];
    float offx = omb[(size_t)(2 * k + 1) * HW + w];
    float mk = omb[(size_t)(18 + k) * HW + w];
    mk = 1.0f / (1.0f + expf(-mk));
    float py = (float)(h - 1 + kh) + offy;
    float px = (float)(w - 1 + kw) + offx;
    float fy0 = floorf(py), fx0 = floorf(px);
    float wy1 = py - fy0, wx1 = px - fx0;
    int y0 = (int)fy0, x0 = (int)fx0;
    int y1 = y0 + 1, x1 = x0 + 1;
    bool vy0 = (y0 >= 0) && (y0 <= HH - 1);
    bool vy1 = (y1 >= 0) && (y1 <= HH - 1);
    bool vx0 = (x0 >= 0) && (x0 <= WW - 1);
    bool vx1 = (x1 >= 0) && (x1 <= WW - 1);
    int y0c = min(max(y0, 0), HH - 1), y1c = min(max(y1, 0), HH - 1);
    int x0c = min(max(x0, 0), WW - 1), x1c = min(max(x1, 0), WW - 1);
    pre_w[k][w][0] = (1.f - wy1) * (1.f - wx1) * mk * ((vy0 && vx0) ? 1.f : 0.f);
    pre_w[k][w][1] = (1.f - wy1) * wx1 * mk * ((vy0 && vx1) ? 1.f : 0.f);
    pre_w[k][w][2] = wy1 * (1.f - wx1) * mk * ((vy1 && vx0) ? 1.f : 0.f);
    pre_w[k][w][3] = wy1 * wx1 * mk * ((vy1 && vx1) ? 1.f : 0.f);
    pre_off[k][w][0] = (y0c * WW + x0c) * CIN;
    pre_off[k][w][1] = (y0c * WW + x1c) * CIN;
    pre_off[k][w][2] = (y1c * WW + x0c) * CIN;
    pre_off[k][w][3] = (y1c * WW + x1c) * CIN;
  }

  f32x4 acc[4][4];
#pragma unroll
  for (int i = 0; i < 4; ++i)
#pragma unroll
    for (int j = 0; j < 4; ++j) acc[i][j] = (f32x4){0.f, 0.f, 0.f, 0.f};

  const unsigned short* xb = xbf + (size_t)b * HW * CIN;
  int p = lane;       // staging pixel
  int cg = wave;      // staging c-group (64 c)
  int l15 = lane & 15, l4 = lane >> 4;
  int pswz = lane & 7;
  int o_base = wave * 64;
  int rowApart = l15 * CIN + l4 * 8;  // A-frag per-lane offset within o-tile

  for (int k = 0; k < 9; ++k) {
    __syncthreads();  // S consumed by previous iter / pre_* ready on first
    // ---- stage S[p][c] for this k (bilinear gather from bf16 NHWC) ----
    {
      const int* po = pre_off[k][p];
      const float* pwp = pre_w[k][p];
      int off0 = po[0], off1 = po[1], off2 = po[2], off3 = po[3];
      float w0 = pwp[0], w1 = pwp[1], w2 = pwp[2], w3 = pwp[3];
#pragma unroll
      for (int cc = 0; cc < 8; ++cc) {
        int c0 = cg * 64 + cc * 8;
        u16x8 v0 = *(const u16x8*)(xb + off0 + c0);
        u16x8 v1 = *(const u16x8*)(xb + off1 + c0);
        u16x8 v2 = *(const u16x8*)(xb + off2 + c0);
        u16x8 v3 = *(const u16x8*)(xb + off3 + c0);
        u16x8 r;
#pragma unroll
        for (int j = 0; j < 8; ++j) {
          float s = w0 * bf2f(v0[j]) + w1 * bf2f(v1[j]) + w2 * bf2f(v2[j]) +
                    w3 * bf2f(v3[j]);
          r[j] = f2bf(s);
        }
        int slot = cg * 8 + (cc ^ pswz);
        *(u16x8*)&S[p][slot * 8] = r;
      }
    }
    __syncthreads();
    // ---- MFMA over K=256 (8 K-steps of 32) ----
    const unsigned short* Wk = Wbf + (size_t)k * COUT * CIN;
#pragma unroll
    for (int ks = 0; ks < 8; ++ks) {
      s16x8 a[4], bf[4];
#pragma unroll
      for (int ot = 0; ot < 4; ++ot)
        a[ot] = *(const s16x8*)(Wk + (o_base + ot * 16) * CIN + ks * 32 + rowApart);
#pragma unroll
      for (int pt = 0; pt < 4; ++pt) {
        int slot = (ks * 4 + l4) ^ pswz;
        bf[pt] = *(const s16x8*)&S[pt * 16 + l15][slot * 8];
      }
#pragma unroll
      for (int ot = 0; ot < 4; ++ot)
#pragma unroll
        for (int pt = 0; pt < 4; ++pt)
          acc[ot][pt] = __builtin_amdgcn_mfma_f32_16x16x32_bf16(a[ot], bf[pt],
                                                                acc[ot][pt], 0, 0, 0);
    }
  }

  // ---- epilogue: BN + ReLU;  C/D: col=lane&15 (p), row=(lane>>4)*4+j (o) ----
#pragma unroll
  for (int ot = 0; ot < 4; ++ot) {
#pragma unroll
    for (int j = 0; j < 4; ++j) {
      int o = o_base + ot * 16 + l4 * 4 + j;
      float sc = bnsc[o], bi = bnbi[o];
      float* ob = out + (((size_t)b * COUT + o) * HH + h) * WW;
#pragma unroll
      for (int pt = 0; pt < 4; ++pt) {
        ob[pt * 16 + l15] = fmaxf(fmaf(acc[ot][pt][j], sc, bi), 0.f);
      }
    }
  }
}

// ---------------------------------------------------------------------------
extern "C" void kernel_launch(void* const* d_in, const int* in_sizes, int n_in,
                              void* d_out, int out_size, void* d_ws, size_t ws_size,
                              hipStream_t stream) {
  const float* x = (const float*)d_in[0];
  const float* off_w = (const float*)d_in[1];
  const float* off_b = (const float*)d_in[2];
  const float* dc_w = (const float*)d_in[3];
  const float* dc_b = (const float*)d_in[4];
  const float* bn_gamma = (const float*)d_in[5];
  const float* bn_beta = (const float*)d_in[6];
  const float* bn_mean = (const float*)d_in[7];
  const float* bn_var = (const float*)d_in[8];
  float* out = (float*)d_out;

  // workspace layout
  char* ws = (char*)d_ws;
  unsigned short* xbf = (unsigned short*)ws;               // 8*4096*256 u16 = 16.78 MB
  ws += (size_t)NB * HW * CIN * sizeof(unsigned short);
  float* om = (float*)ws;                                  // 8*27*4096 f32
  ws += (size_t)NB * 27 * HW * sizeof(float);
  unsigned short* Wbf = (unsigned short*)ws;               // 9*256*256 u16
  ws += (size_t)9 * COUT * CIN * sizeof(unsigned short);
  float* OW2 = (float*)ws;                                 // 256*256 f32
  ws += (size_t)CIN * 256 * sizeof(float);
  float* bnsc = (float*)ws;
  ws += 256 * sizeof(float);
  float* bnbi = (float*)ws;

  k_tr<<<NB * 64 * 4, 256, 0, stream>>>(x, xbf);
  k_wt<<<(9 * COUT * CIN + 255) / 256, 256, 0, stream>>>(dc_w, Wbf);
  k_owt<<<(CIN * 256 + 255) / 256, 256, 0, stream>>>(off_w, OW2);
  k_bn<<<1, 256, 0, stream>>>(bn_gamma, bn_beta, bn_mean, bn_var, dc_b, bnsc, bnbi);
  k_offconv<<<NB * HH, 256, 0, stream>>>(x, OW2, off_b, om);
  k_main<<<NB * HH, 256, 0, stream>>>(xbf, om, Wbf, bnsc, bnbi, out);
}

// Round 4
// 412.004 us; speedup vs baseline: 3.7112x; 1.2326x over previous
//
#include <hip/hip_runtime.h>
#include <hip/hip_bf16.h>
#include <cstdint>
#include <cstddef>

#define HH 64
#define WW 64
#define CIN 256
#define COUT 256
#define NB 8
#define HW (HH * WW)
#define BN_EPS 1e-5f

typedef __attribute__((ext_vector_type(8))) short s16x8;
typedef __attribute__((ext_vector_type(8))) unsigned short u16x8;
typedef __attribute__((ext_vector_type(4))) float f32x4;

static __device__ __forceinline__ float bf2f(unsigned short u) {
  unsigned int v = ((unsigned int)u) << 16;
  return __builtin_bit_cast(float, v);
}
static __device__ __forceinline__ unsigned short f2bf(float f) {
  __hip_bfloat16 h = __float2bfloat16(f);
  return __builtin_bit_cast(unsigned short, h);
}

// ---------------------------------------------------------------------------
// Kernel 1: x NCHW fp32 -> xbf NHWC bf16.
// XCD swizzle: b = bid&7 so image b is transposed on XCD b (pre-warms its L2).
// ---------------------------------------------------------------------------
__global__ __launch_bounds__(256) void k_tr(const float* __restrict__ x,
                                            unsigned short* __restrict__ xbf) {
  __shared__ float tile[64][65];
  int bid = blockIdx.x;
  int b = bid & 7;
  int r = bid >> 3;
  int ct = r & 3;
  int st = r >> 2;
  int lane = threadIdx.x & 63;
  int grp = threadIdx.x >> 6;
  int c0 = ct * 64, s0 = st * 64;
  const float* xb = x + (size_t)b * CIN * HW;
#pragma unroll
  for (int i = 0; i < 16; ++i) {
    int row = grp * 16 + i;
    tile[row][lane] = xb[(size_t)(c0 + row) * HW + s0 + lane];
  }
  __syncthreads();
  unsigned short* xo = xbf + (size_t)b * HW * CIN;
#pragma unroll
  for (int i = 0; i < 16; ++i) {
    int row = grp * 16 + i;
    xo[(size_t)(s0 + row) * CIN + c0 + lane] = f2bf(tile[lane][row]);
  }
}

// ---------------------------------------------------------------------------
// Kernel 2: dc_w [o][c][3][3] fp32 -> Wbf [k][o][c] bf16 (c contiguous)
// ---------------------------------------------------------------------------
__global__ __launch_bounds__(256) void k_wt(const float* __restrict__ dc_w,
                                            unsigned short* __restrict__ Wbf) {
  int idx = blockIdx.x * 256 + threadIdx.x;  // (k*256+o)*256+c
  if (idx >= 9 * COUT * CIN) return;
  int k = idx >> 16;
  int o = (idx >> 8) & 255;
  int c = idx & 255;
  Wbf[idx] = f2bf(dc_w[((size_t)o * CIN + c) * 9 + k]);
}

// ---------------------------------------------------------------------------
// Kernel 3: off_w [ko][c][3][3] -> OW2 [c][256] fp32 (j = ko*9+t, pad 243..255)
// ---------------------------------------------------------------------------
__global__ __launch_bounds__(256) void k_owt(const float* __restrict__ off_w,
                                             float* __restrict__ OW2) {
  int idx = blockIdx.x * 256 + threadIdx.x;
  if (idx >= CIN * 256) return;
  int c = idx >> 8, j = idx & 255;
  float v = 0.f;
  if (j < 243) {
    int ko = j / 9, t = j % 9;
    v = off_w[((size_t)ko * CIN + c) * 9 + t];
  }
  OW2[idx] = v;
}

// ---------------------------------------------------------------------------
// Kernel 4: fold BN + conv bias
// ---------------------------------------------------------------------------
__global__ void k_bn(const float* __restrict__ g, const float* __restrict__ be,
                     const float* __restrict__ m, const float* __restrict__ va,
                     const float* __restrict__ db, float* __restrict__ sc,
                     float* __restrict__ bi) {
  int o = threadIdx.x;
  float s = g[o] * rsqrtf(va[o] + BN_EPS);
  sc[o] = s;
  bi[o] = be[o] + (db[o] - m[o]) * s;
}

// ---------------------------------------------------------------------------
// Kernel 5: offset conv, direct NCHW; scalar weights via readfirstlane.
// XCD swizzle: b = bid&7 (x rows + om stay on XCD b's L2).
// ---------------------------------------------------------------------------
__global__ __launch_bounds__(256) void k_offconv(const float* __restrict__ x,
                                                 const float* __restrict__ OW2,
                                                 const float* __restrict__ off_b,
                                                 float* __restrict__ om) {
  int bid = blockIdx.x;
  int b = bid & 7;
  int h = bid >> 3;
  int w = threadIdx.x & 63;
  int wave = threadIdx.x >> 6;

  float acc[27];
#pragma unroll
  for (int i = 0; i < 27; ++i) acc[i] = 0.f;

  const float* xb = x + (size_t)b * CIN * HW;
  bool up = (h > 0), dn = (h < HH - 1);
  int cb = wave * 64;

  for (int ci = 0; ci < 64; ++ci) {
    int c = cb + ci;
    const float* xc = xb + (size_t)c * HW;
    float r0 = up ? xc[(h - 1) * WW + w] : 0.f;
    float r1 = xc[h * WW + w];
    float r2 = dn ? xc[(h + 1) * WW + w] : 0.f;
    float v[9];
    v[1] = r0; v[4] = r1; v[7] = r2;
    v[0] = __shfl_up(r0, 1);
    v[3] = __shfl_up(r1, 1);
    v[6] = __shfl_up(r2, 1);
    v[2] = __shfl_down(r0, 1);
    v[5] = __shfl_down(r1, 1);
    v[8] = __shfl_down(r2, 1);
    if (w == 0) { v[0] = 0.f; v[3] = 0.f; v[6] = 0.f; }
    if (w == WW - 1) { v[2] = 0.f; v[5] = 0.f; v[8] = 0.f; }
    const float* wk = OW2 + ((size_t)__builtin_amdgcn_readfirstlane(c) << 8);
#pragma unroll
    for (int ko = 0; ko < 27; ++ko) {
#pragma unroll
      for (int t = 0; t < 9; ++t) acc[ko] = fmaf(v[t], wk[ko * 9 + t], acc[ko]);
    }
  }

  __shared__ float red[4][27][64];
#pragma unroll
  for (int ko = 0; ko < 27; ++ko) red[wave][ko][w] = acc[ko];
  __syncthreads();
  for (int idx = threadIdx.x; idx < 27 * 64; idx += 256) {
    int ko = idx >> 6;
    int ww = idx & 63;
    om[(((size_t)b * 27 + ko) * HH + h) * WW + ww] =
        red[0][ko][ww] + red[1][ko][ww] + red[2][ko][ww] + red[3][ko][ww] + off_b[ko];
  }
}

// ---------------------------------------------------------------------------
// Kernel 6: fused deformable conv (bf16 MFMA) + BN + ReLU.
// XCD swizzle: b = bid&7, h = bid>>3 -> XCD b owns image b; working set
// (xbf[b] 2.1MB + W 1.125MB) fits its 4MB private L2.
// ---------------------------------------------------------------------------
__global__ __launch_bounds__(256, 2) void k_main(
    const unsigned short* __restrict__ xbf, const float* __restrict__ om,
    const unsigned short* __restrict__ Wbf, const float* __restrict__ bnsc,
    const float* __restrict__ bnbi, float* __restrict__ out) {
  int bid = blockIdx.x;
  int b = bid & 7;
  int h = bid >> 3;
  int tid = threadIdx.x;
  int lane = tid & 63;
  int wave = tid >> 6;

  __shared__ int pre_off[9][64][4];
  __shared__ float pre_w[9][64][4];
  __shared__ __align__(16) unsigned short S[64][256];

  // ---- precompute per-(k,w) tap offsets + mask-folded bilinear weights ----
  const float* omb = om + ((size_t)b * 27 * HH + h) * WW;
  for (int item = tid; item < 9 * 64; item += 256) {
    int k = item >> 6;
    int w = item & 63;
    int kh = k / 3, kw = k % 3;
    float offy = omb[(size_t)(2 * k) * HW + w];
    float offx = omb[(size_t)(2 * k + 1) * HW + w];
    float mk = omb[(size_t)(18 + k) * HW + w];
    mk = 1.0f / (1.0f + expf(-mk));
    float py = (float)(h - 1 + kh) + offy;
    float px = (float)(w - 1 + kw) + offx;
    float fy0 = floorf(py), fx0 = floorf(px);
    float wy1 = py - fy0, wx1 = px - fx0;
    int y0 = (int)fy0, x0 = (int)fx0;
    int y1 = y0 + 1, x1 = x0 + 1;
    bool vy0 = (y0 >= 0) && (y0 <= HH - 1);
    bool vy1 = (y1 >= 0) && (y1 <= HH - 1);
    bool vx0 = (x0 >= 0) && (x0 <= WW - 1);
    bool vx1 = (x1 >= 0) && (x1 <= WW - 1);
    int y0c = min(max(y0, 0), HH - 1), y1c = min(max(y1, 0), HH - 1);
    int x0c = min(max(x0, 0), WW - 1), x1c = min(max(x1, 0), WW - 1);
    pre_w[k][w][0] = (1.f - wy1) * (1.f - wx1) * mk * ((vy0 && vx0) ? 1.f : 0.f);
    pre_w[k][w][1] = (1.f - wy1) * wx1 * mk * ((vy0 && vx1) ? 1.f : 0.f);
    pre_w[k][w][2] = wy1 * (1.f - wx1) * mk * ((vy1 && vx0) ? 1.f : 0.f);
    pre_w[k][w][3] = wy1 * wx1 * mk * ((vy1 && vx1) ? 1.f : 0.f);
    pre_off[k][w][0] = (y0c * WW + x0c) * CIN;
    pre_off[k][w][1] = (y0c * WW + x1c) * CIN;
    pre_off[k][w][2] = (y1c * WW + x0c) * CIN;
    pre_off[k][w][3] = (y1c * WW + x1c) * CIN;
  }

  f32x4 acc[4][4];
#pragma unroll
  for (int i = 0; i < 4; ++i)
#pragma unroll
    for (int j = 0; j < 4; ++j) acc[i][j] = (f32x4){0.f, 0.f, 0.f, 0.f};

  const unsigned short* xb = xbf + (size_t)b * HW * CIN;
  int p = lane;
  int cg = wave;
  int l15 = lane & 15, l4 = lane >> 4;
  int pswz = lane & 7;
  int o_base = wave * 64;
  int rowApart = l15 * CIN + l4 * 8;

  for (int k = 0; k < 9; ++k) {
    __syncthreads();
    // ---- stage S[p][c] for this k (bilinear gather from bf16 NHWC) ----
    {
      const int* po = pre_off[k][p];
      const float* pwp = pre_w[k][p];
      int off0 = po[0], off1 = po[1], off2 = po[2], off3 = po[3];
      float w0 = pwp[0], w1 = pwp[1], w2 = pwp[2], w3 = pwp[3];
#pragma unroll
      for (int cc = 0; cc < 8; ++cc) {
        int c0 = cg * 64 + cc * 8;
        u16x8 v0 = *(const u16x8*)(xb + off0 + c0);
        u16x8 v1 = *(const u16x8*)(xb + off1 + c0);
        u16x8 v2 = *(const u16x8*)(xb + off2 + c0);
        u16x8 v3 = *(const u16x8*)(xb + off3 + c0);
        u16x8 r;
#pragma unroll
        for (int j = 0; j < 8; ++j) {
          float s = w0 * bf2f(v0[j]) + w1 * bf2f(v1[j]) + w2 * bf2f(v2[j]) +
                    w3 * bf2f(v3[j]);
          r[j] = f2bf(s);
        }
        int slot = cg * 8 + (cc ^ pswz);
        *(u16x8*)&S[p][slot * 8] = r;
      }
    }
    __syncthreads();
    // ---- MFMA over K=256 (8 K-steps of 32) ----
    const unsigned short* Wk = Wbf + (size_t)k * COUT * CIN;
#pragma unroll
    for (int ks = 0; ks < 8; ++ks) {
      s16x8 a[4], bf[4];
#pragma unroll
      for (int ot = 0; ot < 4; ++ot)
        a[ot] = *(const s16x8*)(Wk + (o_base + ot * 16) * CIN + ks * 32 + rowApart);
#pragma unroll
      for (int pt = 0; pt < 4; ++pt) {
        int slot = (ks * 4 + l4) ^ pswz;
        bf[pt] = *(const s16x8*)&S[pt * 16 + l15][slot * 8];
      }
#pragma unroll
      for (int ot = 0; ot < 4; ++ot)
#pragma unroll
        for (int pt = 0; pt < 4; ++pt)
          acc[ot][pt] = __builtin_amdgcn_mfma_f32_16x16x32_bf16(a[ot], bf[pt],
                                                                acc[ot][pt], 0, 0, 0);
    }
  }

  // ---- epilogue: BN + ReLU;  C/D: col=lane&15 (p), row=(lane>>4)*4+j (o) ----
#pragma unroll
  for (int ot = 0; ot < 4; ++ot) {
#pragma unroll
    for (int j = 0; j < 4; ++j) {
      int o = o_base + ot * 16 + l4 * 4 + j;
      float sc = bnsc[o], bi = bnbi[o];
      float* ob = out + (((size_t)b * COUT + o) * HH + h) * WW;
#pragma unroll
      for (int pt = 0; pt < 4; ++pt) {
        ob[pt * 16 + l15] = fmaxf(fmaf(acc[ot][pt][j], sc, bi), 0.f);
      }
    }
  }
}

// ---------------------------------------------------------------------------
extern "C" void kernel_launch(void* const* d_in, const int* in_sizes, int n_in,
                              void* d_out, int out_size, void* d_ws, size_t ws_size,
                              hipStream_t stream) {
  const float* x = (const float*)d_in[0];
  const float* off_w = (const float*)d_in[1];
  const float* off_b = (const float*)d_in[2];
  const float* dc_w = (const float*)d_in[3];
  const float* dc_b = (const float*)d_in[4];
  const float* bn_gamma = (const float*)d_in[5];
  const float* bn_beta = (const float*)d_in[6];
  const float* bn_mean = (const float*)d_in[7];
  const float* bn_var = (const float*)d_in[8];
  float* out = (float*)d_out;

  // workspace layout
  char* ws = (char*)d_ws;
  unsigned short* xbf = (unsigned short*)ws;
  ws += (size_t)NB * HW * CIN * sizeof(unsigned short);
  float* om = (float*)ws;
  ws += (size_t)NB * 27 * HW * sizeof(float);
  unsigned short* Wbf = (unsigned short*)ws;
  ws += (size_t)9 * COUT * CIN * sizeof(unsigned short);
  float* OW2 = (float*)ws;
  ws += (size_t)CIN * 256 * sizeof(float);
  float* bnsc = (float*)ws;
  ws += 256 * sizeof(float);
  float* bnbi = (float*)ws;

  k_tr<<<NB * 64 * 4, 256, 0, stream>>>(x, xbf);
  k_wt<<<(9 * COUT * CIN + 255) / 256, 256, 0, stream>>>(dc_w, Wbf);
  k_owt<<<(CIN * 256 + 255) / 256, 256, 0, stream>>>(off_w, OW2);
  k_bn<<<1, 256, 0, stream>>>(bn_gamma, bn_beta, bn_mean, bn_var, dc_b, bnsc, bnbi);
  k_offconv<<<NB * HH, 256, 0, stream>>>(x, OW2, off_b, om);
  k_main<<<NB * HH, 256, 0, stream>>>(xbf, om, Wbf, bnsc, bnbi, out);
}

// Round 5
// 201.423 us; speedup vs baseline: 7.5912x; 2.0455x over previous
//
#include <hip/hip_runtime.h>
#include <hip/hip_bf16.h>
#include <cstdint>
#include <cstddef>

#define HH 64
#define WW 64
#define CIN 256
#define COUT 256
#define NB 8
#define HW (HH * WW)
#define BN_EPS 1e-5f

typedef __attribute__((ext_vector_type(8))) short s16x8;
typedef __attribute__((ext_vector_type(8))) unsigned short u16x8;
typedef __attribute__((ext_vector_type(4))) float f32x4;

static __device__ __forceinline__ float bf2f(unsigned short u) {
  unsigned int v = ((unsigned int)u) << 16;
  return __builtin_bit_cast(float, v);
}
static __device__ __forceinline__ unsigned short f2bf(float f) {
  __hip_bfloat16 h = __float2bfloat16(f);
  return __builtin_bit_cast(unsigned short, h);
}

// ---------------------------------------------------------------------------
// Kernel 1: x NCHW fp32 -> xbf NHWC bf16.  XCD swizzle: b = bid&7.
// ---------------------------------------------------------------------------
__global__ __launch_bounds__(256) void k_tr(const float* __restrict__ x,
                                            unsigned short* __restrict__ xbf) {
  __shared__ float tile[64][65];
  int bid = blockIdx.x;
  int b = bid & 7;
  int r = bid >> 3;
  int ct = r & 3;
  int st = r >> 2;
  int lane = threadIdx.x & 63;
  int grp = threadIdx.x >> 6;
  int c0 = ct * 64, s0 = st * 64;
  const float* xb = x + (size_t)b * CIN * HW;
#pragma unroll
  for (int i = 0; i < 16; ++i) {
    int row = grp * 16 + i;
    tile[row][lane] = xb[(size_t)(c0 + row) * HW + s0 + lane];
  }
  __syncthreads();
  unsigned short* xo = xbf + (size_t)b * HW * CIN;
#pragma unroll
  for (int i = 0; i < 16; ++i) {
    int row = grp * 16 + i;
    xo[(size_t)(s0 + row) * CIN + c0 + lane] = f2bf(tile[lane][row]);
  }
}

// ---------------------------------------------------------------------------
// Kernel 2: dc_w [o][c][3][3] fp32 -> Wbf [k][o][c] bf16 (c contiguous)
// ---------------------------------------------------------------------------
__global__ __launch_bounds__(256) void k_wt(const float* __restrict__ dc_w,
                                            unsigned short* __restrict__ Wbf) {
  int idx = blockIdx.x * 256 + threadIdx.x;  // (k*256+o)*256+c
  if (idx >= 9 * COUT * CIN) return;
  int k = idx >> 16;
  int o = (idx >> 8) & 255;
  int c = idx & 255;
  Wbf[idx] = f2bf(dc_w[((size_t)o * CIN + c) * 9 + k]);
}

// ---------------------------------------------------------------------------
// Kernel 3: off_w [ko][c][3][3] fp32 -> OWb [t][ko_pad32][c] bf16 (t = kh*3+kw)
// ---------------------------------------------------------------------------
__global__ __launch_bounds__(256) void k_owt(const float* __restrict__ off_w,
                                             unsigned short* __restrict__ OWb) {
  int idx = blockIdx.x * 256 + threadIdx.x;
  if (idx >= 9 * 32 * 256) return;
  int t = idx >> 13;
  int ko = (idx >> 8) & 31;
  int c = idx & 255;
  unsigned short v = 0;
  if (ko < 27) v = f2bf(off_w[((size_t)ko * CIN + c) * 9 + t]);
  OWb[idx] = v;
}

// ---------------------------------------------------------------------------
// Kernel 4: fold BN + conv bias
// ---------------------------------------------------------------------------
__global__ void k_bn(const float* __restrict__ g, const float* __restrict__ be,
                     const float* __restrict__ m, const float* __restrict__ va,
                     const float* __restrict__ db, float* __restrict__ sc,
                     float* __restrict__ bi) {
  int o = threadIdx.x;
  float s = g[o] * rsqrtf(va[o] + BN_EPS);
  sc[o] = s;
  bi[o] = be[o] + (db[o] - m[o]) * s;
}

// ---------------------------------------------------------------------------
// Kernel 5: FUSED offset-conv (MFMA) + deformable conv (MFMA) + BN + ReLU.
// Block = (b,h), XCD swizzle b = bid&7.
// Phase 1: om[27][64] for this row via MFMA over 3 staged input rows.
// Phase 2: bilinear gather -> S, MFMA vs Wbf, BN+ReLU epilogue.
// LDS: ubuf = union(rowbuf[66][256]u16 33.8KB, S[64][256]u16 32KB)
//      + om_lds 6.9KB + pre_off 9.2KB + pre_w 9.2KB = 59.1KB -> 2 blocks/CU.
// ---------------------------------------------------------------------------
__global__ __launch_bounds__(256, 2) void k_main(
    const unsigned short* __restrict__ xbf, const unsigned short* __restrict__ OWb,
    const float* __restrict__ off_b, const unsigned short* __restrict__ Wbf,
    const float* __restrict__ bnsc, const float* __restrict__ bnbi,
    float* __restrict__ out) {
  int bid = blockIdx.x;
  int b = bid & 7;
  int h = bid >> 3;
  int tid = threadIdx.x;
  int lane = tid & 63;
  int wave = tid >> 6;
  int l15 = lane & 15, l4 = lane >> 4;

  __shared__ __align__(16) unsigned short ubuf[66 * 256];
  __shared__ float om_lds[27][64];
  __shared__ int pre_off[9][64][4];
  __shared__ float pre_w[9][64][4];

  const unsigned short* xb = xbf + (size_t)b * HW * CIN;

  // ================= Phase 1: offset conv via MFMA =================
  // zero pad rows 0 and 65 of rowbuf (stay intact through phase 1)
  if (tid < 64) {
    int r = (tid < 32) ? 0 : 65;
    int ch = tid & 31;
    u16x8 z = {0, 0, 0, 0, 0, 0, 0, 0};
    *(u16x8*)&ubuf[r * 256 + ch * 8] = z;
  }

  f32x4 acc_oc[2];
  acc_oc[0] = (f32x4){0.f, 0.f, 0.f, 0.f};
  acc_oc[1] = (f32x4){0.f, 0.f, 0.f, 0.f};
  int wavepx = wave * 16;

  for (int kh = 0; kh < 3; ++kh) {
    int y = h + kh - 1;
    if (y < 0 || y >= HH) continue;  // block-uniform
    __syncthreads();                 // prior readers done (and pads visible)
    // stage row y (32KB contiguous) with XOR swizzle on chunk index
    const unsigned short* src = xb + (size_t)y * WW * CIN;
#pragma unroll
    for (int i = 0; i < 8; ++i) {
      int e8 = i * 256 + tid;  // u16x8 index within row
      int px = e8 >> 5;
      int ch = e8 & 31;
      u16x8 v = *(const u16x8*)(src + e8 * 8);
      *(u16x8*)&ubuf[(px + 1) * 256 + ((ch ^ ((px + 1) & 7)) * 8)] = v;
    }
    __syncthreads();
#pragma unroll
    for (int kw = 0; kw < 3; ++kw) {
      int prow = wavepx + l15 + kw;  // padded row index
      int rs = prow & 7;
      const unsigned short* Atap = OWb + (size_t)(kh * 3 + kw) * 32 * 256;
#pragma unroll
      for (int ks = 0; ks < 8; ++ks) {
        s16x8 bfrag = *(const s16x8*)&ubuf[prow * 256 + (((ks * 4 + l4) ^ rs) * 8)];
#pragma unroll
        for (int kot = 0; kot < 2; ++kot) {
          s16x8 afrag =
              *(const s16x8*)(Atap + (kot * 16 + l15) * 256 + ks * 32 + l4 * 8);
          acc_oc[kot] = __builtin_amdgcn_mfma_f32_16x16x32_bf16(afrag, bfrag,
                                                                acc_oc[kot], 0, 0, 0);
        }
      }
    }
  }
  // write raw conv results (no bias) to om_lds; C/D: col=l15(px), row=l4*4+j(ko)
#pragma unroll
  for (int kot = 0; kot < 2; ++kot) {
#pragma unroll
    for (int j = 0; j < 4; ++j) {
      int ko = kot * 16 + l4 * 4 + j;
      if (ko < 27) om_lds[ko][wavepx + l15] = acc_oc[kot][j];
    }
  }
  __syncthreads();

  // ============ precompute per-(k,w) tap offsets + bilinear weights ============
  for (int item = tid; item < 9 * 64; item += 256) {
    int k = item >> 6;  // wave-uniform
    int w = item & 63;
    int kh = k / 3, kw = k % 3;
    float offy = om_lds[2 * k][w] + off_b[2 * k];
    float offx = om_lds[2 * k + 1][w] + off_b[2 * k + 1];
    float mk = om_lds[18 + k][w] + off_b[18 + k];
    mk = 1.0f / (1.0f + expf(-mk));
    float py = (float)(h - 1 + kh) + offy;
    float px = (float)(w - 1 + kw) + offx;
    float fy0 = floorf(py), fx0 = floorf(px);
    float wy1 = py - fy0, wx1 = px - fx0;
    int y0 = (int)fy0, x0 = (int)fx0;
    int y1 = y0 + 1, x1 = x0 + 1;
    bool vy0 = (y0 >= 0) && (y0 <= HH - 1);
    bool vy1 = (y1 >= 0) && (y1 <= HH - 1);
    bool vx0 = (x0 >= 0) && (x0 <= WW - 1);
    bool vx1 = (x1 >= 0) && (x1 <= WW - 1);
    int y0c = min(max(y0, 0), HH - 1), y1c = min(max(y1, 0), HH - 1);
    int x0c = min(max(x0, 0), WW - 1), x1c = min(max(x1, 0), WW - 1);
    pre_w[k][w][0] = (1.f - wy1) * (1.f - wx1) * mk * ((vy0 && vx0) ? 1.f : 0.f);
    pre_w[k][w][1] = (1.f - wy1) * wx1 * mk * ((vy0 && vx1) ? 1.f : 0.f);
    pre_w[k][w][2] = wy1 * (1.f - wx1) * mk * ((vy1 && vx0) ? 1.f : 0.f);
    pre_w[k][w][3] = wy1 * wx1 * mk * ((vy1 && vx1) ? 1.f : 0.f);
    pre_off[k][w][0] = (y0c * WW + x0c) * CIN;
    pre_off[k][w][1] = (y0c * WW + x1c) * CIN;
    pre_off[k][w][2] = (y1c * WW + x0c) * CIN;
    pre_off[k][w][3] = (y1c * WW + x1c) * CIN;
  }

  // ================= Phase 2: deformable conv =================
  unsigned short(*S)[256] = (unsigned short(*)[256])ubuf;
  f32x4 acc[4][4];
#pragma unroll
  for (int i = 0; i < 4; ++i)
#pragma unroll
    for (int j = 0; j < 4; ++j) acc[i][j] = (f32x4){0.f, 0.f, 0.f, 0.f};

  int p = lane;
  int cg = wave;
  int pswz = lane & 7;
  int o_base = wave * 64;
  int rowApart = l15 * CIN + l4 * 8;

  for (int k = 0; k < 9; ++k) {
    __syncthreads();  // covers precompute visibility (k=0) and S reuse
    // ---- stage S[p][c] for this k (bilinear gather from bf16 NHWC) ----
    {
      const int* po = pre_off[k][p];
      const float* pwp = pre_w[k][p];
      int off0 = po[0], off1 = po[1], off2 = po[2], off3 = po[3];
      float w0 = pwp[0], w1 = pwp[1], w2 = pwp[2], w3 = pwp[3];
#pragma unroll
      for (int cc = 0; cc < 8; ++cc) {
        int c0 = cg * 64 + cc * 8;
        u16x8 v0 = *(const u16x8*)(xb + off0 + c0);
        u16x8 v1 = *(const u16x8*)(xb + off1 + c0);
        u16x8 v2 = *(const u16x8*)(xb + off2 + c0);
        u16x8 v3 = *(const u16x8*)(xb + off3 + c0);
        u16x8 r;
#pragma unroll
        for (int j = 0; j < 8; ++j) {
          float s = w0 * bf2f(v0[j]) + w1 * bf2f(v1[j]) + w2 * bf2f(v2[j]) +
                    w3 * bf2f(v3[j]);
          r[j] = f2bf(s);
        }
        int slot = cg * 8 + (cc ^ pswz);
        *(u16x8*)&S[p][slot * 8] = r;
      }
    }
    __syncthreads();
    // ---- MFMA over K=256 (8 K-steps of 32) ----
    const unsigned short* Wk = Wbf + (size_t)k * COUT * CIN;
#pragma unroll
    for (int ks = 0; ks < 8; ++ks) {
      s16x8 a[4], bf[4];
#pragma unroll
      for (int ot = 0; ot < 4; ++ot)
        a[ot] = *(const s16x8*)(Wk + (o_base + ot * 16) * CIN + ks * 32 + rowApart);
#pragma unroll
      for (int pt = 0; pt < 4; ++pt) {
        int slot = (ks * 4 + l4) ^ pswz;
        bf[pt] = *(const s16x8*)&S[pt * 16 + l15][slot * 8];
      }
#pragma unroll
      for (int ot = 0; ot < 4; ++ot)
#pragma unroll
        for (int pt = 0; pt < 4; ++pt)
          acc[ot][pt] = __builtin_amdgcn_mfma_f32_16x16x32_bf16(a[ot], bf[pt],
                                                                acc[ot][pt], 0, 0, 0);
    }
  }

  // ---- epilogue: BN + ReLU;  C/D: col=lane&15 (p), row=(lane>>4)*4+j (o) ----
#pragma unroll
  for (int ot = 0; ot < 4; ++ot) {
#pragma unroll
    for (int j = 0; j < 4; ++j) {
      int o = o_base + ot * 16 + l4 * 4 + j;
      float sc = bnsc[o], bi = bnbi[o];
      float* ob = out + (((size_t)b * COUT + o) * HH + h) * WW;
#pragma unroll
      for (int pt = 0; pt < 4; ++pt) {
        ob[pt * 16 + l15] = fmaxf(fmaf(acc[ot][pt][j], sc, bi), 0.f);
      }
    }
  }
}

// ---------------------------------------------------------------------------
extern "C" void kernel_launch(void* const* d_in, const int* in_sizes, int n_in,
                              void* d_out, int out_size, void* d_ws, size_t ws_size,
                              hipStream_t stream) {
  const float* x = (const float*)d_in[0];
  const float* off_w = (const float*)d_in[1];
  const float* off_b = (const float*)d_in[2];
  const float* dc_w = (const float*)d_in[3];
  const float* dc_b = (const float*)d_in[4];
  const float* bn_gamma = (const float*)d_in[5];
  const float* bn_beta = (const float*)d_in[6];
  const float* bn_mean = (const float*)d_in[7];
  const float* bn_var = (const float*)d_in[8];
  float* out = (float*)d_out;

  // workspace layout
  char* ws = (char*)d_ws;
  unsigned short* xbf = (unsigned short*)ws;  // 16.78 MB
  ws += (size_t)NB * HW * CIN * sizeof(unsigned short);
  unsigned short* Wbf = (unsigned short*)ws;  // 1.18 MB
  ws += (size_t)9 * COUT * CIN * sizeof(unsigned short);
  unsigned short* OWb = (unsigned short*)ws;  // 147 KB
  ws += (size_t)9 * 32 * 256 * sizeof(unsigned short);
  float* bnsc = (float*)ws;
  ws += 256 * sizeof(float);
  float* bnbi = (float*)ws;

  k_tr<<<NB * 64 * 4, 256, 0, stream>>>(x, xbf);
  k_wt<<<(9 * COUT * CIN + 255) / 256, 256, 0, stream>>>(dc_w, Wbf);
  k_owt<<<(9 * 32 * 256 + 255) / 256, 256, 0, stream>>>(off_w, OWb);
  k_bn<<<1, 256, 0, stream>>>(bn_gamma, bn_beta, bn_mean, bn_var, dc_b, bnsc, bnbi);
  k_main<<<NB * HH, 256, 0, stream>>>(xbf, OWb, off_b, Wbf, bnsc, bnbi, out);
}

// Round 6
// 128.718 us; speedup vs baseline: 11.8789x; 1.5648x over previous
//
#include <hip/hip_runtime.h>
#include <hip/hip_bf16.h>
#include <cstdint>
#include <cstddef>

#define HH 64
#define WW 64
#define CIN 256
#define COUT 256
#define NB 8
#define HW (HH * WW)
#define BN_EPS 1e-5f

typedef __attribute__((ext_vector_type(8))) short s16x8;
typedef __attribute__((ext_vector_type(8))) unsigned short u16x8;
typedef __attribute__((ext_vector_type(4))) float f32x4;

static __device__ __forceinline__ float bf2f(unsigned short u) {
  unsigned int v = ((unsigned int)u) << 16;
  return __builtin_bit_cast(float, v);
}
static __device__ __forceinline__ unsigned short f2bf(float f) {
  __hip_bfloat16 h = __float2bfloat16(f);
  return __builtin_bit_cast(unsigned short, h);
}
static __device__ __forceinline__ u16x8 shfl32(u16x8 v) {
  int4 a = __builtin_bit_cast(int4, v);
  int4 r;
  r.x = __shfl_xor(a.x, 32, 64);
  r.y = __shfl_xor(a.y, 32, 64);
  r.z = __shfl_xor(a.z, 32, 64);
  r.w = __shfl_xor(a.w, 32, 64);
  return __builtin_bit_cast(u16x8, r);
}

// ---------------------------------------------------------------------------
// Kernel 1: x NCHW fp32 -> xbf NHWC bf16.  XCD swizzle: b = bid&7.
// ---------------------------------------------------------------------------
__global__ __launch_bounds__(256) void k_tr(const float* __restrict__ x,
                                            unsigned short* __restrict__ xbf) {
  __shared__ float tile[64][65];
  int bid = blockIdx.x;
  int b = bid & 7;
  int r = bid >> 3;
  int ct = r & 3;
  int st = r >> 2;
  int lane = threadIdx.x & 63;
  int grp = threadIdx.x >> 6;
  int c0 = ct * 64, s0 = st * 64;
  const float* xb = x + (size_t)b * CIN * HW;
#pragma unroll
  for (int i = 0; i < 16; ++i) {
    int row = grp * 16 + i;
    tile[row][lane] = xb[(size_t)(c0 + row) * HW + s0 + lane];
  }
  __syncthreads();
  unsigned short* xo = xbf + (size_t)b * HW * CIN;
#pragma unroll
  for (int i = 0; i < 16; ++i) {
    int row = grp * 16 + i;
    xo[(size_t)(s0 + row) * CIN + c0 + lane] = f2bf(tile[lane][row]);
  }
}

// ---------------------------------------------------------------------------
// Kernel 2: dc_w [o][c][3][3] fp32 -> Wf in MFMA FRAGMENT ORDER:
// Wf[k][ks][tile][lane][j]  (tile=o/16, lane: o%16 = lane&15, c = ks*32+(lane>>4)*8+j)
// -> every A-frag load in k_main is base + lane*16B (coalesced 1KB).
// ---------------------------------------------------------------------------
__global__ __launch_bounds__(256) void k_wt(const float* __restrict__ dc_w,
                                            unsigned short* __restrict__ Wf) {
  int idx = blockIdx.x * 256 + threadIdx.x;
  if (idx >= 9 * 8 * 16 * 64 * 8) return;
  int j = idx & 7;
  int lane = (idx >> 3) & 63;
  int tile = (idx >> 9) & 15;
  int ks = (idx >> 13) & 7;
  int k = idx >> 16;
  int o = tile * 16 + (lane & 15);
  int c = ks * 32 + (lane >> 4) * 8 + j;
  Wf[idx] = f2bf(dc_w[((size_t)o * CIN + c) * 9 + k]);
}

// ---------------------------------------------------------------------------
// Kernel 3: off_w [ko][c][3][3] fp32 -> OWf fragment order:
// OWf[t][ks][kot][lane][j]  (ko = kot*16 + (lane&15), c = ks*32+(lane>>4)*8+j)
// ---------------------------------------------------------------------------
__global__ __launch_bounds__(256) void k_owt(const float* __restrict__ off_w,
                                             unsigned short* __restrict__ OWf) {
  int idx = blockIdx.x * 256 + threadIdx.x;
  if (idx >= 9 * 8 * 2 * 64 * 8) return;
  int j = idx & 7;
  int lane = (idx >> 3) & 63;
  int kot = (idx >> 9) & 1;
  int ks = (idx >> 10) & 7;
  int t = idx >> 13;
  int ko = kot * 16 + (lane & 15);
  int c = ks * 32 + (lane >> 4) * 8 + j;
  unsigned short v = 0;
  if (ko < 27) v = f2bf(off_w[((size_t)ko * CIN + c) * 9 + t]);
  OWf[idx] = v;
}

// ---------------------------------------------------------------------------
// Kernel 4: fold BN + conv bias
// ---------------------------------------------------------------------------
__global__ void k_bn(const float* __restrict__ g, const float* __restrict__ be,
                     const float* __restrict__ m, const float* __restrict__ va,
                     const float* __restrict__ db, float* __restrict__ sc,
                     float* __restrict__ bi) {
  int o = threadIdx.x;
  float s = g[o] * rsqrtf(va[o] + BN_EPS);
  sc[o] = s;
  bi[o] = be[o] + (db[o] - m[o]) * s;
}

// ---------------------------------------------------------------------------
// Kernel 5: FUSED offset-conv (MFMA) + deformable conv (MFMA) + BN + ReLU.
// All global vector loads are coalesced: A-frags via fragment-ordered Wf/OWf,
// bilinear gather via per-pixel tap-vector loads + lane-half butterfly.
// ---------------------------------------------------------------------------
__global__ __launch_bounds__(256, 2) void k_main(
    const unsigned short* __restrict__ xbf, const unsigned short* __restrict__ OWf,
    const float* __restrict__ off_b, const unsigned short* __restrict__ Wf,
    const float* __restrict__ bnsc, const float* __restrict__ bnbi,
    float* __restrict__ out) {
  int bid = blockIdx.x;
  int b = bid & 7;
  int h = bid >> 3;
  int tid = threadIdx.x;
  int lane = tid & 63;
  int wave = tid >> 6;
  int l15 = lane & 15, l4 = lane >> 4;

  __shared__ __align__(16) unsigned short ubuf[66 * 256];
  __shared__ float om_lds[27][64];
  __shared__ int pre_off[9][64][4];
  __shared__ float pre_w[9][64][4];

  const unsigned short* xb = xbf + (size_t)b * HW * CIN;

  // ================= Phase 1: offset conv via MFMA =================
  if (tid < 64) {
    int r = (tid < 32) ? 0 : 65;
    int ch = tid & 31;
    u16x8 z = {0, 0, 0, 0, 0, 0, 0, 0};
    *(u16x8*)&ubuf[r * 256 + ch * 8] = z;
  }

  f32x4 acc_oc[2];
  acc_oc[0] = (f32x4){0.f, 0.f, 0.f, 0.f};
  acc_oc[1] = (f32x4){0.f, 0.f, 0.f, 0.f};
  int wavepx = wave * 16;

  for (int kh = 0; kh < 3; ++kh) {
    int y = h + kh - 1;
    if (y < 0 || y >= HH) continue;  // block-uniform
    __syncthreads();
    const unsigned short* src = xb + (size_t)y * WW * CIN;
#pragma unroll
    for (int i = 0; i < 8; ++i) {
      int e8 = i * 256 + tid;
      int px = e8 >> 5;
      int ch = e8 & 31;
      u16x8 v = *(const u16x8*)(src + e8 * 8);
      *(u16x8*)&ubuf[(px + 1) * 256 + ((ch ^ ((px + 1) & 7)) * 8)] = v;
    }
    __syncthreads();
#pragma unroll
    for (int kw = 0; kw < 3; ++kw) {
      int prow = wavepx + l15 + kw;
      int rs = prow & 7;
      const unsigned short* Atap = OWf + ((size_t)(kh * 3 + kw) * 8) * 1024 + lane * 8;
#pragma unroll
      for (int ks = 0; ks < 8; ++ks) {
        s16x8 bfrag = *(const s16x8*)&ubuf[prow * 256 + (((ks * 4 + l4) ^ rs) * 8)];
#pragma unroll
        for (int kot = 0; kot < 2; ++kot) {
          s16x8 afrag = *(const s16x8*)(Atap + ks * 1024 + kot * 512);
          acc_oc[kot] = __builtin_amdgcn_mfma_f32_16x16x32_bf16(afrag, bfrag,
                                                                acc_oc[kot], 0, 0, 0);
        }
      }
    }
  }
#pragma unroll
  for (int kot = 0; kot < 2; ++kot) {
#pragma unroll
    for (int j = 0; j < 4; ++j) {
      int ko = kot * 16 + l4 * 4 + j;
      if (ko < 27) om_lds[ko][wavepx + l15] = acc_oc[kot][j];
    }
  }
  __syncthreads();

  // ============ precompute per-(k,w) tap offsets + bilinear weights ============
  for (int item = tid; item < 9 * 64; item += 256) {
    int k = item >> 6;
    int w = item & 63;
    int kh = k / 3, kw = k % 3;
    float offy = om_lds[2 * k][w] + off_b[2 * k];
    float offx = om_lds[2 * k + 1][w] + off_b[2 * k + 1];
    float mk = om_lds[18 + k][w] + off_b[18 + k];
    mk = 1.0f / (1.0f + expf(-mk));
    float py = (float)(h - 1 + kh) + offy;
    float px = (float)(w - 1 + kw) + offx;
    float fy0 = floorf(py), fx0 = floorf(px);
    float wy1 = py - fy0, wx1 = px - fx0;
    int y0 = (int)fy0, x0 = (int)fx0;
    int y1 = y0 + 1, x1 = x0 + 1;
    bool vy0 = (y0 >= 0) && (y0 <= HH - 1);
    bool vy1 = (y1 >= 0) && (y1 <= HH - 1);
    bool vx0 = (x0 >= 0) && (x0 <= WW - 1);
    bool vx1 = (x1 >= 0) && (x1 <= WW - 1);
    int y0c = min(max(y0, 0), HH - 1), y1c = min(max(y1, 0), HH - 1);
    int x0c = min(max(x0, 0), WW - 1), x1c = min(max(x1, 0), WW - 1);
    pre_w[k][w][0] = (1.f - wy1) * (1.f - wx1) * mk * ((vy0 && vx0) ? 1.f : 0.f);
    pre_w[k][w][1] = (1.f - wy1) * wx1 * mk * ((vy0 && vx1) ? 1.f : 0.f);
    pre_w[k][w][2] = wy1 * (1.f - wx1) * mk * ((vy1 && vx0) ? 1.f : 0.f);
    pre_w[k][w][3] = wy1 * wx1 * mk * ((vy1 && vx1) ? 1.f : 0.f);
    pre_off[k][w][0] = (y0c * WW + x0c) * CIN;
    pre_off[k][w][1] = (y0c * WW + x1c) * CIN;
    pre_off[k][w][2] = (y1c * WW + x0c) * CIN;
    pre_off[k][w][3] = (y1c * WW + x1c) * CIN;
  }

  // ================= Phase 2: deformable conv =================
  unsigned short(*S)[256] = (unsigned short(*)[256])ubuf;
  f32x4 acc[4][4];
#pragma unroll
  for (int i = 0; i < 4; ++i)
#pragma unroll
    for (int j = 0; j < 4; ++j) acc[i][j] = (f32x4){0.f, 0.f, 0.f, 0.f};

  int pswz = lane & 7;
  int o_base = wave * 64;
  int half = lane >> 5;
  int chunk = lane & 31;

  for (int k = 0; k < 9; ++k) {
    __syncthreads();
    // ---- stage S: coalesced tap-vector loads + lane-half butterfly ----
    {
#pragma unroll 4
      for (int pp = 0; pp < 16; ++pp) {
        int px = wavepx + pp;
        int oA = pre_off[k][px][half];
        float wA = pre_w[k][px][half];
        int oB = pre_off[k][px][2 + half];
        float wB = pre_w[k][px][2 + half];
        u16x8 vA = *(const u16x8*)(xb + oA + chunk * 8);
        u16x8 vB = *(const u16x8*)(xb + oB + chunk * 8);
        u16x8 sA = shfl32(vA);
        u16x8 sB = shfl32(vB);
        float wsA = __shfl_xor(wA, 32, 64);
        float wsB = __shfl_xor(wB, 32, 64);
        u16x8 r;
#pragma unroll
        for (int j = 0; j < 8; ++j) {
          float s = wA * bf2f(vA[j]) + wsA * bf2f(sA[j]) + wB * bf2f(vB[j]) +
                    wsB * bf2f(sB[j]);
          r[j] = f2bf(s);
        }
        if (lane < 32) {
          int phys = (chunk & 24) | ((chunk ^ px) & 7);
          *(u16x8*)&S[px][phys * 8] = r;
        }
      }
    }
    __syncthreads();
    // ---- MFMA over K=256 (8 K-steps of 32); A-frags coalesced from Wf ----
    const unsigned short* Wa = Wf + (size_t)k * 65536 + (wave * 4) * 512 + lane * 8;
#pragma unroll
    for (int ks = 0; ks < 8; ++ks) {
      s16x8 a[4], bf[4];
#pragma unroll
      for (int ot = 0; ot < 4; ++ot)
        a[ot] = *(const s16x8*)(Wa + ks * 8192 + ot * 512);
#pragma unroll
      for (int pt = 0; pt < 4; ++pt) {
        int slot = (ks * 4 + l4) ^ pswz;
        bf[pt] = *(const s16x8*)&S[pt * 16 + l15][slot * 8];
      }
#pragma unroll
      for (int ot = 0; ot < 4; ++ot)
#pragma unroll
        for (int pt = 0; pt < 4; ++pt)
          acc[ot][pt] = __builtin_amdgcn_mfma_f32_16x16x32_bf16(a[ot], bf[pt],
                                                                acc[ot][pt], 0, 0, 0);
    }
  }

  // ---- epilogue: BN + ReLU;  C/D: col=lane&15 (p), row=(lane>>4)*4+j (o) ----
#pragma unroll
  for (int ot = 0; ot < 4; ++ot) {
#pragma unroll
    for (int j = 0; j < 4; ++j) {
      int o = o_base + ot * 16 + l4 * 4 + j;
      float sc = bnsc[o], bi = bnbi[o];
      float* ob = out + (((size_t)b * COUT + o) * HH + h) * WW;
#pragma unroll
      for (int pt = 0; pt < 4; ++pt) {
        ob[pt * 16 + l15] = fmaxf(fmaf(acc[ot][pt][j], sc, bi), 0.f);
      }
    }
  }
}

// ---------------------------------------------------------------------------
extern "C" void kernel_launch(void* const* d_in, const int* in_sizes, int n_in,
                              void* d_out, int out_size, void* d_ws, size_t ws_size,
                              hipStream_t stream) {
  const float* x = (const float*)d_in[0];
  const float* off_w = (const float*)d_in[1];
  const float* off_b = (const float*)d_in[2];
  const float* dc_w = (const float*)d_in[3];
  const float* dc_b = (const float*)d_in[4];
  const float* bn_gamma = (const float*)d_in[5];
  const float* bn_beta = (const float*)d_in[6];
  const float* bn_mean = (const float*)d_in[7];
  const float* bn_var = (const float*)d_in[8];
  float* out = (float*)d_out;

  // workspace layout
  char* ws = (char*)d_ws;
  unsigned short* xbf = (unsigned short*)ws;  // 16.78 MB
  ws += (size_t)NB * HW * CIN * sizeof(unsigned short);
  unsigned short* Wf = (unsigned short*)ws;  // 1.18 MB
  ws += (size_t)9 * 8 * 16 * 64 * 8 * sizeof(unsigned short);
  unsigned short* OWf = (unsigned short*)ws;  // 147 KB
  ws += (size_t)9 * 8 * 2 * 64 * 8 * sizeof(unsigned short);
  float* bnsc = (float*)ws;
  ws += 256 * sizeof(float);
  float* bnbi = (float*)ws;

  k_tr<<<NB * 64 * 4, 256, 0, stream>>>(x, xbf);
  k_wt<<<(9 * 8 * 16 * 64 * 8 + 255) / 256, 256, 0, stream>>>(dc_w, Wf);
  k_owt<<<(9 * 8 * 2 * 64 * 8 + 255) / 256, 256, 0, stream>>>(off_w, OWf);
  k_bn<<<1, 256, 0, stream>>>(bn_gamma, bn_beta, bn_mean, bn_var, dc_b, bnsc, bnbi);
  k_main<<<NB * HH, 256, 0, stream>>>(xbf, OWf, off_b, Wf, bnsc, bnbi, out);
}

// Round 7
// 107.410 us; speedup vs baseline: 14.2356x; 1.1984x over previous
//
#include <hip/hip_runtime.h>
#include <hip/hip_bf16.h>
#include <hip/hip_fp16.h>
#include <cstdint>
#include <cstddef>

#define HH 64
#define WW 64
#define CIN 256
#define COUT 256
#define NB 8
#define HW (HH * WW)
#define BN_EPS 1e-5f

typedef __attribute__((ext_vector_type(8))) short s16x8;
typedef __attribute__((ext_vector_type(8))) unsigned short u16x8;
typedef __attribute__((ext_vector_type(4))) float f32x4;

static __device__ __forceinline__ float bf2f(unsigned short u) {
  unsigned int v = ((unsigned int)u) << 16;
  return __builtin_bit_cast(float, v);
}
static __device__ __forceinline__ unsigned short f2bf(float f) {
  __hip_bfloat16 h = __float2bfloat16(f);
  return __builtin_bit_cast(unsigned short, h);
}

// ---------------------------------------------------------------------------
// Kernel 1: x NCHW fp32 -> xbf NHWC bf16.  XCD swizzle: b = bid&7.
// ---------------------------------------------------------------------------
__global__ __launch_bounds__(256) void k_tr(const float* __restrict__ x,
                                            unsigned short* __restrict__ xbf) {
  __shared__ float tile[64][65];
  int bid = blockIdx.x;
  int b = bid & 7;
  int r = bid >> 3;
  int ct = r & 3;
  int st = r >> 2;
  int lane = threadIdx.x & 63;
  int grp = threadIdx.x >> 6;
  int c0 = ct * 64, s0 = st * 64;
  const float* xb = x + (size_t)b * CIN * HW;
#pragma unroll
  for (int i = 0; i < 16; ++i) {
    int row = grp * 16 + i;
    tile[row][lane] = xb[(size_t)(c0 + row) * HW + s0 + lane];
  }
  __syncthreads();
  unsigned short* xo = xbf + (size_t)b * HW * CIN;
#pragma unroll
  for (int i = 0; i < 16; ++i) {
    int row = grp * 16 + i;
    xo[(size_t)(s0 + row) * CIN + c0 + lane] = f2bf(tile[lane][row]);
  }
}

// ---------------------------------------------------------------------------
// Kernel 2: dc_w [o][c][3][3] fp32 -> Wf in MFMA FRAGMENT ORDER:
// Wf[k][ks][tile][lane][j]  (o = tile*16+(lane&15), c = ks*32+(lane>>4)*8+j)
// ---------------------------------------------------------------------------
__global__ __launch_bounds__(256) void k_wt(const float* __restrict__ dc_w,
                                            unsigned short* __restrict__ Wf) {
  int idx = blockIdx.x * 256 + threadIdx.x;
  if (idx >= 9 * 8 * 16 * 64 * 8) return;
  int j = idx & 7;
  int lane = (idx >> 3) & 63;
  int tile = (idx >> 9) & 15;
  int ks = (idx >> 13) & 7;
  int k = idx >> 16;
  int o = tile * 16 + (lane & 15);
  int c = ks * 32 + (lane >> 4) * 8 + j;
  Wf[idx] = f2bf(dc_w[((size_t)o * CIN + c) * 9 + k]);
}

// ---------------------------------------------------------------------------
// Kernel 3: off_w [ko][c][3][3] fp32 -> OWf fragment order:
// OWf[t][ks][kot][lane][j]  (ko = kot*16 + (lane&15), c = ks*32+(lane>>4)*8+j)
// ---------------------------------------------------------------------------
__global__ __launch_bounds__(256) void k_owt(const float* __restrict__ off_w,
                                             unsigned short* __restrict__ OWf) {
  int idx = blockIdx.x * 256 + threadIdx.x;
  if (idx >= 9 * 8 * 2 * 64 * 8) return;
  int j = idx & 7;
  int lane = (idx >> 3) & 63;
  int kot = (idx >> 9) & 1;
  int ks = (idx >> 10) & 7;
  int t = idx >> 13;
  int ko = kot * 16 + (lane & 15);
  int c = ks * 32 + (lane >> 4) * 8 + j;
  unsigned short v = 0;
  if (ko < 27) v = f2bf(off_w[((size_t)ko * CIN + c) * 9 + t]);
  OWf[idx] = v;
}

// ---------------------------------------------------------------------------
// Kernel 4: fold BN + conv bias
// ---------------------------------------------------------------------------
__global__ void k_bn(const float* __restrict__ g, const float* __restrict__ be,
                     const float* __restrict__ m, const float* __restrict__ va,
                     const float* __restrict__ db, float* __restrict__ sc,
                     float* __restrict__ bi) {
  int o = threadIdx.x;
  float s = g[o] * rsqrtf(va[o] + BN_EPS);
  sc[o] = s;
  bi[o] = be[o] + (db[o] - m[o]) * s;
}

// ---------------------------------------------------------------------------
// Kernel 5: FUSED offset-conv (MFMA) + deformable conv (MFMA) + BN + ReLU.
// Staging: 2 pixels/pass, each lane combines all 4 taps locally (no shuffles).
// LDS 48.8KB -> 3 blocks/CU.
// ---------------------------------------------------------------------------
__global__ __launch_bounds__(256, 3) void k_main(
    const unsigned short* __restrict__ xbf, const unsigned short* __restrict__ OWf,
    const float* __restrict__ off_b, const unsigned short* __restrict__ Wf,
    const float* __restrict__ bnsc, const float* __restrict__ bnbi,
    float* __restrict__ out) {
  int bid = blockIdx.x;
  int b = bid & 7;
  int h = bid >> 3;
  int tid = threadIdx.x;
  int lane = tid & 63;
  int wave = tid >> 6;
  int l15 = lane & 15, l4 = lane >> 4;

  __shared__ __align__(16) unsigned short ubuf[66 * 256];  // 33.8KB
  __shared__ float om_lds[27][64];                         // 6.9KB
  __shared__ unsigned short pre_offS[9][64][4];            // 4.6KB (pixel idx)
  __shared__ __half pre_wH[9][64][4];                      // 4.6KB

  const unsigned short* xb = xbf + (size_t)b * HW * CIN;

  // ================= Phase 1: offset conv via MFMA =================
  if (tid < 64) {
    int r = (tid < 32) ? 0 : 65;
    int ch = tid & 31;
    u16x8 z = {0, 0, 0, 0, 0, 0, 0, 0};
    *(u16x8*)&ubuf[r * 256 + ch * 8] = z;
  }

  f32x4 acc_oc[2];
  acc_oc[0] = (f32x4){0.f, 0.f, 0.f, 0.f};
  acc_oc[1] = (f32x4){0.f, 0.f, 0.f, 0.f};
  int wavepx = wave * 16;

  for (int kh = 0; kh < 3; ++kh) {
    int y = h + kh - 1;
    if (y < 0 || y >= HH) continue;  // block-uniform
    __syncthreads();
    const unsigned short* src = xb + (size_t)y * WW * CIN;
#pragma unroll
    for (int i = 0; i < 8; ++i) {
      int e8 = i * 256 + tid;
      int px = e8 >> 5;
      int ch = e8 & 31;
      u16x8 v = *(const u16x8*)(src + e8 * 8);
      *(u16x8*)&ubuf[(px + 1) * 256 + ((ch ^ ((px + 1) & 7)) * 8)] = v;
    }
    __syncthreads();
#pragma unroll
    for (int kw = 0; kw < 3; ++kw) {
      int prow = wavepx + l15 + kw;
      int rs = prow & 7;
      const unsigned short* Atap = OWf + ((size_t)(kh * 3 + kw) * 8) * 1024 + lane * 8;
#pragma unroll
      for (int ks = 0; ks < 8; ++ks) {
        s16x8 bfrag = *(const s16x8*)&ubuf[prow * 256 + (((ks * 4 + l4) ^ rs) * 8)];
#pragma unroll
        for (int kot = 0; kot < 2; ++kot) {
          s16x8 afrag = *(const s16x8*)(Atap + ks * 1024 + kot * 512);
          acc_oc[kot] = __builtin_amdgcn_mfma_f32_16x16x32_bf16(afrag, bfrag,
                                                                acc_oc[kot], 0, 0, 0);
        }
      }
    }
  }
#pragma unroll
  for (int kot = 0; kot < 2; ++kot) {
#pragma unroll
    for (int j = 0; j < 4; ++j) {
      int ko = kot * 16 + l4 * 4 + j;
      if (ko < 27) om_lds[ko][wavepx + l15] = acc_oc[kot][j];
    }
  }
  __syncthreads();

  // ============ precompute per-(k,w) tap pixel-idx + weights ============
  for (int item = tid; item < 9 * 64; item += 256) {
    int k = item >> 6;
    int w = item & 63;
    int kh = k / 3, kw = k % 3;
    float offy = om_lds[2 * k][w] + off_b[2 * k];
    float offx = om_lds[2 * k + 1][w] + off_b[2 * k + 1];
    float mk = om_lds[18 + k][w] + off_b[18 + k];
    mk = 1.0f / (1.0f + expf(-mk));
    float py = (float)(h - 1 + kh) + offy;
    float px = (float)(w - 1 + kw) + offx;
    float fy0 = floorf(py), fx0 = floorf(px);
    float wy1 = py - fy0, wx1 = px - fx0;
    int y0 = (int)fy0, x0 = (int)fx0;
    int y1 = y0 + 1, x1 = x0 + 1;
    bool vy0 = (y0 >= 0) && (y0 <= HH - 1);
    bool vy1 = (y1 >= 0) && (y1 <= HH - 1);
    bool vx0 = (x0 >= 0) && (x0 <= WW - 1);
    bool vx1 = (x1 >= 0) && (x1 <= WW - 1);
    int y0c = min(max(y0, 0), HH - 1), y1c = min(max(y1, 0), HH - 1);
    int x0c = min(max(x0, 0), WW - 1), x1c = min(max(x1, 0), WW - 1);
    pre_wH[k][w][0] =
        __float2half((1.f - wy1) * (1.f - wx1) * mk * ((vy0 && vx0) ? 1.f : 0.f));
    pre_wH[k][w][1] = __float2half((1.f - wy1) * wx1 * mk * ((vy0 && vx1) ? 1.f : 0.f));
    pre_wH[k][w][2] = __float2half(wy1 * (1.f - wx1) * mk * ((vy1 && vx0) ? 1.f : 0.f));
    pre_wH[k][w][3] = __float2half(wy1 * wx1 * mk * ((vy1 && vx1) ? 1.f : 0.f));
    pre_offS[k][w][0] = (unsigned short)(y0c * WW + x0c);
    pre_offS[k][w][1] = (unsigned short)(y0c * WW + x1c);
    pre_offS[k][w][2] = (unsigned short)(y1c * WW + x0c);
    pre_offS[k][w][3] = (unsigned short)(y1c * WW + x1c);
  }

  // ================= Phase 2: deformable conv =================
  unsigned short(*S)[256] = (unsigned short(*)[256])ubuf;
  f32x4 acc[4][4];
#pragma unroll
  for (int i = 0; i < 4; ++i)
#pragma unroll
    for (int j = 0; j < 4; ++j) acc[i][j] = (f32x4){0.f, 0.f, 0.f, 0.f};

  int pswz = lane & 7;
  int o_base = wave * 64;
  int hv = lane >> 5;     // pixel select within pass
  int chunk = lane & 31;  // 8-channel chunk

  for (int k = 0; k < 9; ++k) {
    __syncthreads();
    // ---- stage S: 2 pixels/pass, all 4 taps per lane, no cross-lane ----
    {
#pragma unroll
      for (int pp = 0; pp < 8; ++pp) {
        int px = wavepx + pp * 2 + hv;
        int i0 = ((int)pre_offS[k][px][0]) << 8;
        int i1 = ((int)pre_offS[k][px][1]) << 8;
        int i2 = ((int)pre_offS[k][px][2]) << 8;
        int i3 = ((int)pre_offS[k][px][3]) << 8;
        float w0 = __half2float(pre_wH[k][px][0]);
        float w1 = __half2float(pre_wH[k][px][1]);
        float w2 = __half2float(pre_wH[k][px][2]);
        float w3 = __half2float(pre_wH[k][px][3]);
        u16x8 v0 = *(const u16x8*)(xb + i0 + chunk * 8);
        u16x8 v1 = *(const u16x8*)(xb + i1 + chunk * 8);
        u16x8 v2 = *(const u16x8*)(xb + i2 + chunk * 8);
        u16x8 v3 = *(const u16x8*)(xb + i3 + chunk * 8);
        u16x8 r;
#pragma unroll
        for (int j = 0; j < 8; ++j) {
          float s = w0 * bf2f(v0[j]) + w1 * bf2f(v1[j]) + w2 * bf2f(v2[j]) +
                    w3 * bf2f(v3[j]);
          r[j] = f2bf(s);
        }
        int phys = chunk ^ (px & 7);
        *(u16x8*)&S[px][phys * 8] = r;
      }
    }
    __syncthreads();
    // ---- MFMA over K=256 (8 K-steps of 32); A-frags coalesced from Wf ----
    const unsigned short* Wa = Wf + (size_t)k * 65536 + (wave * 4) * 512 + lane * 8;
#pragma unroll
    for (int ks = 0; ks < 8; ++ks) {
      s16x8 a[4], bf[4];
#pragma unroll
      for (int ot = 0; ot < 4; ++ot)
        a[ot] = *(const s16x8*)(Wa + ks * 8192 + ot * 512);
#pragma unroll
      for (int pt = 0; pt < 4; ++pt) {
        int slot = (ks * 4 + l4) ^ pswz;
        bf[pt] = *(const s16x8*)&S[pt * 16 + l15][slot * 8];
      }
#pragma unroll
      for (int ot = 0; ot < 4; ++ot)
#pragma unroll
        for (int pt = 0; pt < 4; ++pt)
          acc[ot][pt] = __builtin_amdgcn_mfma_f32_16x16x32_bf16(a[ot], bf[pt],
                                                                acc[ot][pt], 0, 0, 0);
    }
  }

  // ---- epilogue: BN + ReLU;  C/D: col=lane&15 (p), row=(lane>>4)*4+j (o) ----
#pragma unroll
  for (int ot = 0; ot < 4; ++ot) {
#pragma unroll
    for (int j = 0; j < 4; ++j) {
      int o = o_base + ot * 16 + l4 * 4 + j;
      float sc = bnsc[o], bi = bnbi[o];
      float* ob = out + (((size_t)b * COUT + o) * HH + h) * WW;
#pragma unroll
      for (int pt = 0; pt < 4; ++pt) {
        ob[pt * 16 + l15] = fmaxf(fmaf(acc[ot][pt][j], sc, bi), 0.f);
      }
    }
  }
}

// ---------------------------------------------------------------------------
extern "C" void kernel_launch(void* const* d_in, const int* in_sizes, int n_in,
                              void* d_out, int out_size, void* d_ws, size_t ws_size,
                              hipStream_t stream) {
  const float* x = (const float*)d_in[0];
  const float* off_w = (const float*)d_in[1];
  const float* off_b = (const float*)d_in[2];
  const float* dc_w = (const float*)d_in[3];
  const float* dc_b = (const float*)d_in[4];
  const float* bn_gamma = (const float*)d_in[5];
  const float* bn_beta = (const float*)d_in[6];
  const float* bn_mean = (const float*)d_in[7];
  const float* bn_var = (const float*)d_in[8];
  float* out = (float*)d_out;

  // workspace layout
  char* ws = (char*)d_ws;
  unsigned short* xbf = (unsigned short*)ws;  // 16.78 MB
  ws += (size_t)NB * HW * CIN * sizeof(unsigned short);
  unsigned short* Wf = (unsigned short*)ws;  // 1.18 MB
  ws += (size_t)9 * 8 * 16 * 64 * 8 * sizeof(unsigned short);
  unsigned short* OWf = (unsigned short*)ws;  // 147 KB
  ws += (size_t)9 * 8 * 2 * 64 * 8 * sizeof(unsigned short);
  float* bnsc = (float*)ws;
  ws += 256 * sizeof(float);
  float* bnbi = (float*)ws;

  k_tr<<<NB * 64 * 4, 256, 0, stream>>>(x, xbf);
  k_wt<<<(9 * 8 * 16 * 64 * 8 + 255) / 256, 256, 0, stream>>>(dc_w, Wf);
  k_owt<<<(9 * 8 * 2 * 64 * 8 + 255) / 256, 256, 0, stream>>>(off_w, OWf);
  k_bn<<<1, 256, 0, stream>>>(bn_gamma, bn_beta, bn_mean, bn_var, dc_b, bnsc, bnbi);
  k_main<<<NB * HH, 256, 0, stream>>>(xbf, OWf, off_b, Wf, bnsc, bnbi, out);
}